// Round 6
// baseline (413.331 us; speedup 1.0000x reference)
//
#include <hip/hip_runtime.h>
#include <hip/hip_bf16.h>

#define D_MODEL 1024
#define N_HEAD 16
#define BSZ 2
#define QLEN 2048
#define LOCAL_SIZE 1000
#define QKV3 (3 * N_HEAD * 64) // 3072

typedef __hip_bfloat16 bf16;
typedef short bf16x8 __attribute__((ext_vector_type(8)));
typedef float f32x4 __attribute__((ext_vector_type(4)));

static __device__ __forceinline__ float b2f(bf16 x) { return __bfloat162float(x); }
static __device__ __forceinline__ float bits2f(unsigned short u) {
    return __uint_as_float(((unsigned int)u) << 16);
}
static __device__ __forceinline__ unsigned short f2bs(float x) {
    __hip_bfloat16 h = __float2bfloat16(x);
    return *(unsigned short*)&h;
}

// mode: 0 = always bf16, 1 = always fp32, 2 = follow runtime flag (raw harness tensor)
static __device__ __forceinline__ int rmode(int m, int fl) { return (m == 2) ? fl : m; }
static __device__ __forceinline__ float ldm(const void* p, size_t i, int isf) {
    return isf ? ((const float*)p)[i] : b2f(((const bf16*)p)[i]);
}
static __device__ __forceinline__ float4 ld4(const void* p, size_t i, int isf) {
    if (isf) return ((const float4*)p)[i >> 2];
    ushort4 u = ((const ushort4*)p)[i >> 2];
    float4 f;
    f.x = bits2f(u.x); f.y = bits2f(u.y); f.z = bits2f(u.z); f.w = bits2f(u.w);
    return f;
}
static __device__ __forceinline__ ushort4 cvt4(float4 f) {
    ushort4 u;
    u.x = f2bs(f.x); u.y = f2bs(f.y); u.z = f2bs(f.z); u.w = f2bs(f.w);
    return u;
}

// async global->LDS, 16 B per lane; LDS dest = wave-uniform base + lane*16
static __device__ __forceinline__ void glds16(const bf16* g, unsigned short* l) {
    __builtin_amdgcn_global_load_lds(
        (const __attribute__((address_space(1))) void*)g,
        (__attribute__((address_space(3))) void*)l,
        16, 0, 0);
}

// ---------------------------------------------------------------------------
// dtype detector (flag: 0 = bf16 data, 1 = fp32 data). Proven.
// ---------------------------------------------------------------------------
__global__ void detect_kernel(const unsigned short* __restrict__ w, int* __restrict__ flag)
{
    if (threadIdx.x == 0 && blockIdx.x == 0) {
        int good = 0;
        for (int i = 0; i < 256; ++i) {
            float v = bits2f(w[i]);
            if (v == v && fabsf(v) < 8.0f) ++good;
        }
        *flag = (good >= 240) ? 0 : 1;
    }
}

// ---------------------------------------------------------------------------
// Fused weight convert: Wqkv|Wr|Wo (raw) -> contiguous bf16 at wqb.
// ---------------------------------------------------------------------------
__global__ __launch_bounds__(256)
void convw_all(const void* __restrict__ wq, const void* __restrict__ wr,
               const void* __restrict__ wo, bf16* __restrict__ outp,
               const int* __restrict__ flag)
{
    const int fl = *flag;
    const int blk = blockIdx.x;
    const void* in; size_t segOff;
    if (blk < 1536)      { in = wq; segOff = (size_t)blk * 2048; }
    else if (blk < 2048) { in = wr; segOff = (size_t)(blk - 1536) * 2048; }
    else                 { in = wo; segOff = (size_t)(blk - 2048) * 2048; }
    const size_t ii = segOff + (size_t)threadIdx.x * 8;
    const size_t oi = (size_t)blk * 2048 + (size_t)threadIdx.x * 8;
    if (fl) {
        float4 a = ((const float4*)in)[ii / 4];
        float4 b = ((const float4*)in)[ii / 4 + 1];
        *(ushort4*)((unsigned short*)outp + oi)     = cvt4(a);
        *(ushort4*)((unsigned short*)outp + oi + 4) = cvt4(b);
    } else {
        *(uint4*)((unsigned short*)outp + oi) = ((const uint4*)in)[ii / 8];
    }
}

// ---------------------------------------------------------------------------
// Fused transpose+convert: z1ss (z<BSZ) and pos (z==BSZ) -> [q][d] bf16.
// ---------------------------------------------------------------------------
__global__ __launch_bounds__(256)
void tcvt_all(const void* __restrict__ z1ss, const void* __restrict__ pos,
              bf16* __restrict__ zt, bf16* __restrict__ post,
              const int* __restrict__ flag)
{
    const int fl = *flag;
    const int zb = blockIdx.z;
    const void* in = (zb < BSZ) ? z1ss : pos;
    const size_t inOff = (zb < BSZ) ? (size_t)zb * D_MODEL * QLEN : 0;
    bf16* outp = (zb < BSZ) ? zt + (size_t)zb * QLEN * D_MODEL : post;
    const int c0 = blockIdx.x * 32;   // col (q) in [0, QLEN)
    const int r0 = blockIdx.y * 32;   // row (d) in [0, D_MODEL)
    const int tx = threadIdx.x & 31, ty = threadIdx.x >> 5;
    __shared__ float T[32][33];
#pragma unroll
    for (int r = 0; r < 4; ++r) {
        int rr = r0 + ty + r * 8;
        T[ty + r * 8][tx] = ldm(in, inOff + (size_t)rr * QLEN + c0 + tx, fl);
    }
    __syncthreads();
#pragma unroll
    for (int r = 0; r < 4; ++r) {
        int cc = c0 + ty + r * 8;
        outp[(size_t)cc * D_MODEL + r0 + tx] = __float2bfloat16(T[tx][ty + r * 8]);
    }
}

// ---------------------------------------------------------------------------
// Fused QKV + rhk GEMM, glds-staged (proven structure from round 3).
// ---------------------------------------------------------------------------
__global__ __launch_bounds__(256)
void gemm_qkvr(const bf16* __restrict__ wqb, const bf16* __restrict__ wrb,
               const bf16* __restrict__ zt, const bf16* __restrict__ post,
               bf16* __restrict__ wh, bf16* __restrict__ rhk,
               const void* __restrict__ u1ss, const int* __restrict__ flag)
{
    const int fl = *flag;
    const int bz = blockIdx.z;
    const int by = blockIdx.y;
    const bool isR = by >= (QKV3 / 128);
    if (isR && bz) return;
    const int n0 = blockIdx.x * 128;
    const int m0 = (isR ? by - QKV3 / 128 : by) * 128;
    const int K = D_MODEL, N = QLEN;

    const bf16* A = isR ? wrb : wqb;
    const bf16* B = isR ? post : zt + (size_t)bz * (size_t)QLEN * D_MODEL;
    bf16* C       = isR ? rhk  : wh + (size_t)bz * (size_t)QKV3 * QLEN;
    const size_t uOff = (size_t)bz * (size_t)QKV3 * QLEN;

    const int tid = threadIdx.x;
    const int wave = tid >> 6, lane = tid & 63;
    const int quad = lane >> 4, l15 = lane & 15;
    const int wm = (wave >> 1) * 64, wn = (wave & 1) * 64;

    __shared__ __align__(16) unsigned short A_s[2][128 * 32];
    __shared__ __align__(16) unsigned short B_s[2][128 * 32];

    const int srow = wave * 32 + (lane >> 2);
    const int scol = (lane & 3) * 8;
    const bf16* Ag = A + (size_t)(m0 + srow) * K + scol;
    const bf16* Bg = B + (size_t)(n0 + srow) * K + scol;
    const int sbase = wave * 1024;

    f32x4 acc[4][4];
#pragma unroll
    for (int i = 0; i < 4; ++i)
#pragma unroll
        for (int j = 0; j < 4; ++j) acc[i][j] = (f32x4){0.f, 0.f, 0.f, 0.f};

    glds16(Ag,                   &A_s[0][sbase]);
    glds16(Ag + (size_t)16 * K,  &A_s[0][sbase + 512]);
    glds16(Bg,                   &B_s[0][sbase]);
    glds16(Bg + (size_t)16 * K,  &B_s[0][sbase + 512]);

    int cur = 0;
    for (int k0 = 0; k0 < K; k0 += 32) {
        __syncthreads();
        if (k0 + 32 < K) {
            const int kn = k0 + 32;
            glds16(Ag + kn,                  &A_s[cur ^ 1][sbase]);
            glds16(Ag + (size_t)16 * K + kn, &A_s[cur ^ 1][sbase + 512]);
            glds16(Bg + kn,                  &B_s[cur ^ 1][sbase]);
            glds16(Bg + (size_t)16 * K + kn, &B_s[cur ^ 1][sbase + 512]);
        }
        bf16x8 a[4], bb[4];
#pragma unroll
        for (int i = 0; i < 4; ++i)
            a[i] = *(const bf16x8*)&A_s[cur][(wm + i * 16 + l15) * 32 + quad * 8];
#pragma unroll
        for (int j = 0; j < 4; ++j)
            bb[j] = *(const bf16x8*)&B_s[cur][(wn + j * 16 + l15) * 32 + quad * 8];
#pragma unroll
        for (int i = 0; i < 4; ++i)
#pragma unroll
            for (int j = 0; j < 4; ++j)
                acc[i][j] = __builtin_amdgcn_mfma_f32_16x16x32_bf16(a[i], bb[j], acc[i][j], 0, 0, 0);
        cur ^= 1;
    }

#pragma unroll
    for (int i = 0; i < 4; ++i) {
#pragma unroll
        for (int j = 0; j < 4; ++j) {
            int n = n0 + wn + j * 16 + l15;
#pragma unroll
            for (int r = 0; r < 4; ++r) {
                int m = m0 + wm + i * 16 + quad * 4 + r;
                float v = acc[i][j][r];
                if (!isR) v += ldm(u1ss, uOff + (size_t)m * N + n, fl);
                C[(size_t)m * N + n] = __float2bfloat16(v);
            }
        }
    }
}

// ---------------------------------------------------------------------------
// m97-style GEMM: global_load_lds staging, double-buffered LDS (round-3 proven).
// ---------------------------------------------------------------------------
__global__ __launch_bounds__(256)
void gemm_glds(const bf16* __restrict__ A, size_t sAb,
               const bf16* __restrict__ B, size_t sBb,
               void* __restrict__ C, int c_is_bf16, size_t sCb,
               const void* __restrict__ addm, int mAdd, size_t sAddb,
               const void* __restrict__ bias, int mBias,
               int M, int N, int K, const int* __restrict__ flag)
{
    const int fl = *flag;
    const int fAdd = rmode(mAdd, fl), fBias = rmode(mBias, fl);

    const int bz = blockIdx.z;
    const int n0 = blockIdx.x * 128;
    const int m0 = blockIdx.y * 128;
    const int tid = threadIdx.x;
    const int wave = tid >> 6, lane = tid & 63;
    const int quad = lane >> 4, l15 = lane & 15;
    const int wm = (wave >> 1) * 64, wn = (wave & 1) * 64;

    __shared__ __align__(16) unsigned short A_s[2][128 * 32];
    __shared__ __align__(16) unsigned short B_s[2][128 * 32];

    const int srow = wave * 32 + (lane >> 2);
    const int scol = (lane & 3) * 8;
    const bf16* Ag = A + (size_t)bz * sAb + (size_t)(m0 + srow) * K + scol;
    const bf16* Bg = B + (size_t)bz * sBb + (size_t)(n0 + srow) * K + scol;
    const int sbase = wave * 1024;

    f32x4 acc[4][4];
#pragma unroll
    for (int i = 0; i < 4; ++i)
#pragma unroll
        for (int j = 0; j < 4; ++j) acc[i][j] = (f32x4){0.f, 0.f, 0.f, 0.f};

    glds16(Ag,                   &A_s[0][sbase]);
    glds16(Ag + (size_t)16 * K,  &A_s[0][sbase + 512]);
    glds16(Bg,                   &B_s[0][sbase]);
    glds16(Bg + (size_t)16 * K,  &B_s[0][sbase + 512]);

    int cur = 0;
    for (int k0 = 0; k0 < K; k0 += 32) {
        __syncthreads();
        if (k0 + 32 < K) {
            const int kn = k0 + 32;
            glds16(Ag + kn,                  &A_s[cur ^ 1][sbase]);
            glds16(Ag + (size_t)16 * K + kn, &A_s[cur ^ 1][sbase + 512]);
            glds16(Bg + kn,                  &B_s[cur ^ 1][sbase]);
            glds16(Bg + (size_t)16 * K + kn, &B_s[cur ^ 1][sbase + 512]);
        }
        bf16x8 a[4], bb[4];
#pragma unroll
        for (int i = 0; i < 4; ++i)
            a[i] = *(const bf16x8*)&A_s[cur][(wm + i * 16 + l15) * 32 + quad * 8];
#pragma unroll
        for (int j = 0; j < 4; ++j)
            bb[j] = *(const bf16x8*)&B_s[cur][(wn + j * 16 + l15) * 32 + quad * 8];
#pragma unroll
        for (int i = 0; i < 4; ++i)
#pragma unroll
            for (int j = 0; j < 4; ++j)
                acc[i][j] = __builtin_amdgcn_mfma_f32_16x16x32_bf16(a[i], bb[j], acc[i][j], 0, 0, 0);
        cur ^= 1;
    }

    const size_t cb = (size_t)bz * sCb;
#pragma unroll
    for (int i = 0; i < 4; ++i) {
#pragma unroll
        for (int j = 0; j < 4; ++j) {
            int n = n0 + wn + j * 16 + l15;
#pragma unroll
            for (int r = 0; r < 4; ++r) {
                int m = m0 + wm + i * 16 + quad * 4 + r;
                float v = acc[i][j][r];
                if (addm) v += ldm(addm, (size_t)bz * sAddb + (size_t)m * N + n, fAdd);
                if (bias) v += ldm(bias, (size_t)n, fBias);
                size_t ci = cb + (size_t)m * N + n;
                if (c_is_bf16) ((bf16*)C)[ci] = __float2bfloat16(v);
                else           ((float*)C)[ci] = v;
            }
        }
    }
}

// ---------------------------------------------------------------------------
// Software-pipelined MFMA TN-GEMM (tier-2 fallback, proven).
// ---------------------------------------------------------------------------
__global__ __launch_bounds__(256)
void gemm_bf16(const void* __restrict__ A, int mA, size_t sAb,
               const void* __restrict__ B, int mB, size_t sBb,
               void* __restrict__ C, int c_is_bf16, size_t sCb,
               const void* __restrict__ addm, int mAdd, size_t sAddb,
               const void* __restrict__ bias, int mBias,
               int M, int N, int K, const int* __restrict__ flag)
{
    const int fl = *flag;
    const int fA = rmode(mA, fl), fB = rmode(mB, fl);
    const int fAdd = rmode(mAdd, fl), fBias = rmode(mBias, fl);

    const int bz = blockIdx.z;
    const int n0 = blockIdx.x * 128;
    const int m0 = blockIdx.y * 128;
    const int tid = threadIdx.x;
    const int wave = tid >> 6, lane = tid & 63;
    const int quad = lane >> 4, l15 = lane & 15;
    const int wm = (wave >> 1) * 64, wn = (wave & 1) * 64;

    __shared__ unsigned short A_s[128][40];
    __shared__ unsigned short B_s[128][40];

    const int r0c = tid >> 2,         c0c = tid & 3;
    const int r1c = (tid + 256) >> 2, c1c = tid & 3;

    const size_t aOff = (size_t)bz * sAb;
    const size_t bOff = (size_t)bz * sBb;
    const bf16*  Ah = (const bf16*)A;
    const float* Af = (const float*)A;
    const bf16*  Bh = (const bf16*)B;
    const float* Bf = (const float*)B;

    uint4 pa[4], pb[4];

#define LOAD_OP(p, fX, Xh, Xf, xOff, R0, C0, R1, C1, base, k0)                          \
    do {                                                                                \
        if (!fX) {                                                                      \
            p[0] = *(const uint4*)(Xh + xOff + (size_t)(base + R0) * K + (k0) + C0 * 8);\
            p[1] = *(const uint4*)(Xh + xOff + (size_t)(base + R1) * K + (k0) + C1 * 8);\
        } else {                                                                        \
            const float* q0 = Xf + xOff + (size_t)(base + R0) * K + (k0) + C0 * 8;      \
            const float* q1 = Xf + xOff + (size_t)(base + R1) * K + (k0) + C1 * 8;      \
            p[0] = *(const uint4*)q0; p[1] = *(const uint4*)(q0 + 4);                   \
            p[2] = *(const uint4*)q1; p[3] = *(const uint4*)(q1 + 4);                   \
        }                                                                               \
    } while (0)

#define WRITE_OP(p, fX, S, R0, C0, R1, C1)                                              \
    do {                                                                                \
        if (!fX) {                                                                      \
            *(uint4*)&S[R0][C0 * 8] = p[0];                                             \
            *(uint4*)&S[R1][C1 * 8] = p[1];                                             \
        } else {                                                                        \
            float4 f0 = *(float4*)&p[0], f1 = *(float4*)&p[1];                          \
            float4 f2 = *(float4*)&p[2], f3 = *(float4*)&p[3];                          \
            *(ushort4*)&S[R0][C0 * 8]     = cvt4(f0);                                   \
            *(ushort4*)&S[R0][C0 * 8 + 4] = cvt4(f1);                                   \
            *(ushort4*)&S[R1][C1 * 8]     = cvt4(f2);                                   \
            *(ushort4*)&S[R1][C1 * 8 + 4] = cvt4(f3);                                   \
        }                                                                               \
    } while (0)

    f32x4 acc[4][4];
#pragma unroll
    for (int i = 0; i < 4; ++i)
#pragma unroll
        for (int j = 0; j < 4; ++j) acc[i][j] = (f32x4){0.f, 0.f, 0.f, 0.f};

    LOAD_OP(pa, fA, Ah, Af, aOff, r0c, c0c, r1c, c1c, m0, 0);
    LOAD_OP(pb, fB, Bh, Bf, bOff, r0c, c0c, r1c, c1c, n0, 0);

    for (int k0 = 0; k0 < K; k0 += 32) {
        WRITE_OP(pa, fA, A_s, r0c, c0c, r1c, c1c);
        WRITE_OP(pb, fB, B_s, r0c, c0c, r1c, c1c);
        __syncthreads();

        const int kn = k0 + 32;
        if (kn < K) {
            LOAD_OP(pa, fA, Ah, Af, aOff, r0c, c0c, r1c, c1c, m0, kn);
            LOAD_OP(pb, fB, Bh, Bf, bOff, r0c, c0c, r1c, c1c, n0, kn);
        }

        bf16x8 a[4], bb[4];
#pragma unroll
        for (int i = 0; i < 4; ++i)
            a[i] = *(const bf16x8*)&A_s[wm + i * 16 + l15][quad * 8];
#pragma unroll
        for (int j = 0; j < 4; ++j)
            bb[j] = *(const bf16x8*)&B_s[wn + j * 16 + l15][quad * 8];
#pragma unroll
        for (int i = 0; i < 4; ++i)
#pragma unroll
            for (int j = 0; j < 4; ++j)
                acc[i][j] = __builtin_amdgcn_mfma_f32_16x16x32_bf16(a[i], bb[j], acc[i][j], 0, 0, 0);
        __syncthreads();
    }
#undef LOAD_OP
#undef WRITE_OP

    const size_t cb = (size_t)bz * sCb;
#pragma unroll
    for (int i = 0; i < 4; ++i) {
#pragma unroll
        for (int j = 0; j < 4; ++j) {
            int n = n0 + wn + j * 16 + l15;
#pragma unroll
            for (int r = 0; r < 4; ++r) {
                int m = m0 + wm + i * 16 + quad * 4 + r;
                float v = acc[i][j][r];
                if (addm) v += ldm(addm, (size_t)bz * sAddb + (size_t)m * N + n, fAdd);
                if (bias) v += ldm(bias, (size_t)n, fBias);
                size_t ci = cb + (size_t)m * N + n;
                if (c_is_bf16) ((bf16*)C)[ci] = __float2bfloat16(v);
                else           ((float*)C)[ci] = v;
            }
        }
    }
}

// ---------------------------------------------------------------------------
// Old MFMA TN-GEMM (small-workspace fallback only).
// ---------------------------------------------------------------------------
__global__ __launch_bounds__(256)
void gemm_tn(const void* __restrict__ A, int mA, size_t sAb,
             const void* __restrict__ Bsrc, int mB, int bTrans, int ldB, size_t sBb,
             void* __restrict__ C, int c_is_bf16, size_t sCb,
             const void* __restrict__ addm, int mAdd, int addT, size_t sAddb,
             const void* __restrict__ bias, int mBias,
             int M, int N, int K, const int* __restrict__ flag)
{
    const int fl = *flag;
    const int fA = rmode(mA, fl), fB = rmode(mB, fl);
    const int fAdd = rmode(mAdd, fl), fBias = rmode(mBias, fl);

    const int bz = blockIdx.z;
    const int n0 = blockIdx.x * 128;
    const int m0 = blockIdx.y * 128;
    const int tid = threadIdx.x;
    const int wave = tid >> 6, lane = tid & 63;
    const int quad = lane >> 4, l15 = lane & 15;
    const int wm = (wave >> 1) * 64, wn = (wave & 1) * 64;

    __shared__ unsigned short A_s[128][40];
    __shared__ unsigned short B_s[128][40];

    const size_t aBase = (size_t)bz * sAb;
    const size_t bBase = (size_t)bz * sBb;

    f32x4 acc[4][4];
#pragma unroll
    for (int i = 0; i < 4; ++i)
#pragma unroll
        for (int j = 0; j < 4; ++j) acc[i][j] = (f32x4){0.f, 0.f, 0.f, 0.f};

    for (int k0 = 0; k0 < K; k0 += 32) {
#pragma unroll
        for (int g = 0; g < 4; ++g) {
            int c = tid + g * 256;
            int m = c >> 3, kc = (c & 7) * 4;
            float4 f = ld4(A, aBase + (size_t)(m0 + m) * K + k0 + kc, fA);
            *(ushort4*)&A_s[m][kc] = cvt4(f);
        }
        if (!bTrans) {
#pragma unroll
            for (int g = 0; g < 4; ++g) {
                int c = tid + g * 256;
                int n = c >> 3, kc = (c & 7) * 4;
                float4 f = ld4(Bsrc, bBase + (size_t)(n0 + n) * ldB + k0 + kc, fB);
                *(ushort4*)&B_s[n][kc] = cvt4(f);
            }
        } else {
#pragma unroll
            for (int g = 0; g < 4; ++g) {
                int c = tid + g * 256;
                int k = c >> 5, nc = (c & 31) * 4;
                float4 f = ld4(Bsrc, bBase + (size_t)(k0 + k) * ldB + n0 + nc, fB);
                ushort4 u = cvt4(f);
                B_s[nc + 0][k] = u.x;
                B_s[nc + 1][k] = u.y;
                B_s[nc + 2][k] = u.z;
                B_s[nc + 3][k] = u.w;
            }
        }
        __syncthreads();

        bf16x8 a[4], bb[4];
#pragma unroll
        for (int i = 0; i < 4; ++i)
            a[i] = *(const bf16x8*)&A_s[wm + i * 16 + l15][quad * 8];
#pragma unroll
        for (int j = 0; j < 4; ++j)
            bb[j] = *(const bf16x8*)&B_s[wn + j * 16 + l15][quad * 8];
#pragma unroll
        for (int i = 0; i < 4; ++i)
#pragma unroll
            for (int j = 0; j < 4; ++j)
                acc[i][j] = __builtin_amdgcn_mfma_f32_16x16x32_bf16(a[i], bb[j], acc[i][j], 0, 0, 0);
        __syncthreads();
    }

    const size_t cb = (size_t)bz * sCb;
#pragma unroll
    for (int i = 0; i < 4; ++i) {
#pragma unroll
        for (int j = 0; j < 4; ++j) {
            int n = n0 + wn + j * 16 + l15;
#pragma unroll
            for (int r = 0; r < 4; ++r) {
                int m = m0 + wm + i * 16 + quad * 4 + r;
                float v = acc[i][j][r];
                if (addm) {
                    size_t ai = (size_t)bz * sAddb +
                                (addT ? ((size_t)n * M + m) : ((size_t)m * N + n));
                    v += ldm(addm, ai, fAdd);
                }
                if (bias) v += ldm(bias, (size_t)n, fBias);
                size_t ci = cb + (size_t)m * N + n;
                if (c_is_bf16) ((bf16*)C)[ci] = __float2bfloat16(v);
                else           ((float*)C)[ci] = v;
            }
        }
    }
}

// ---------------------------------------------------------------------------
// MFMA banded flash attention v7:
//  Round-5 diagnosis: the "prefetch" was issued right before barrier (b), and
//  __syncthreads compiles to s_waitcnt vmcnt(0) lgkmcnt(0) + s_barrier -> the
//  barrier DRAINED the prefetch immediately. Loads never overlapped compute;
//  each iteration ate the full HBM/L3 latency inside (b). Explains invariance
//  to all occupancy levers (rounds 0-5) + MfmaUtil 6.6% + VALUBusy 23%.
//  v7 (T4 counted waits, m201-proven pattern): in-loop barriers become raw
//  __builtin_amdgcn_s_barrier():
//   (a) raw (prior-phase LDS reads all consumed by MFMA-dep lgkm waits)
//   (b) s_waitcnt lgkmcnt(0) + raw (ds_writes visible; vmcnt NOT drained ->
//       K/V/R prefetch rides through, consumed next iter with compiler's
//       own counted vmcnt wait)
//   (c) raw (Rt reads pinned by MFMA deps; Gs/Ps accesses are wave-local)
// ---------------------------------------------------------------------------
__global__ __launch_bounds__(256)
void attn_mfma(const bf16* __restrict__ wh,  // [B][3072][Q]
               const bf16* __restrict__ rhk, // [1024][Q]
               const void* __restrict__ rwb, // [1024] raw
               const void* __restrict__ rrb, // [1024] raw
               bf16* __restrict__ av_out,    // [B][Q][1024]
               const int* __restrict__ flag)
{
    const int fl = *flag;
    const int it = blockIdx.x, h = blockIdx.y, b = blockIdx.z;
    const int i0 = it * 64;
    const int tid = threadIdx.x;
    const int wave = tid >> 6, lane = tid & 63;
    const int quad = lane >> 4, l15 = lane & 15;
    const int hw = h * 64;

    __shared__ __align__(16) unsigned short sm[18944]; // 37,888 B
    unsigned short* KtPs = sm;          // [64][72]: K^T tile [j][d], then P [i][j]
    unsigned short* Vs   = sm + 4608;   // [64][72]: V tile [d][j]
    unsigned short* Rt   = sm + 9216;   // [64][72]: new R half [t][d] (overlaid by Gs)
    unsigned short* Gs   = sm + 9216;   // [128][76] t-major: Gs[t*76 + i]
    unsigned short* Qrw  = sm;          // init-only overlay
    unsigned short* Qrr  = sm + 4608;   // init-only overlay

    const bf16* whb = wh + (size_t)b * QKV3 * QLEN;
    const int d_t = tid & 63;
    const int dv0 = tid >> 3, jv0 = (tid & 7) * 8;
    const int dv1 = (tid + 256) >> 3;

    int lo = i0 - (LOCAL_SIZE - 1);
    if (lo < 0) lo = 0;
    const int jt_lo = lo >> 6;
    const int j0_lo = jt_lo * 64;

    // ---- stage Q (+biases) and initial R lower half; all loads first ----
    {
        float brw = ldm(rwb, hw + d_t, fl);
        float brr = ldm(rrb, hw + d_t, fl);
        const bf16* qrow = whb + (size_t)(hw + d_t) * QLEN + i0;
        uint4 qv0 = *(const uint4*)(qrow + wave * 8);
        uint4 qv1 = *(const uint4*)(qrow + (4 + wave) * 8);
        // initial window cols t in [0,64): p = pbase0 + t; provably in [922,2047]
        const int pbase0 = j0_lo - i0 + QLEN - 64;
        const bf16* rrow = rhk + (size_t)(hw + d_t) * QLEN;
        uint4 rv0i = *(const uint4*)(rrow + pbase0 + wave * 8);
        uint4 rv1i = *(const uint4*)(rrow + pbase0 + (4 + wave) * 8);

        unsigned short u8[8];
        *(uint4*)u8 = qv0;
#pragma unroll
        for (int u = 0; u < 8; ++u) {
            float q = bits2f(u8[u]);
            Qrw[(wave * 8 + u) * 72 + d_t] = f2bs(q + brw);
            Qrr[(wave * 8 + u) * 72 + d_t] = f2bs(q + brr);
        }
        *(uint4*)u8 = qv1;
#pragma unroll
        for (int u = 0; u < 8; ++u) {
            float q = bits2f(u8[u]);
            Qrw[((4 + wave) * 8 + u) * 72 + d_t] = f2bs(q + brw);
            Qrr[((4 + wave) * 8 + u) * 72 + d_t] = f2bs(q + brr);
        }
        *(uint4*)u8 = rv0i;
#pragma unroll
        for (int u = 0; u < 8; ++u) Rt[(wave * 8 + u) * 72 + d_t] = u8[u];
        *(uint4*)u8 = rv1i;
#pragma unroll
        for (int u = 0; u < 8; ++u) Rt[((4 + wave) * 8 + u) * 72 + d_t] = u8[u];
    }

    // ---- prefetch first tile's K/V/R into registers (T14) ----
    uint4 kv0, kv1, vv0, vv1, rv0, rv1;
    {
        const int j0 = j0_lo;
        const bf16* krow = whb + (size_t)(1024 + hw + d_t) * QLEN + j0;
        kv0 = *(const uint4*)(krow + wave * 8);
        kv1 = *(const uint4*)(krow + (4 + wave) * 8);
        vv0 = *(const uint4*)(whb + (size_t)(2048 + hw + dv0) * QLEN + j0 + jv0);
        vv1 = *(const uint4*)(whb + (size_t)(2048 + hw + dv1) * QLEN + j0 + jv0);
        const int pn = j0 - i0 + QLEN;
        const bf16* rrow = rhk + (size_t)(hw + d_t) * QLEN;
        int p0 = pn + wave * 8;
        if (p0 + 7 < QLEN) rv0 = *(const uint4*)(rrow + p0);
        else {
            unsigned short u8[8];
#pragma unroll
            for (int u = 0; u < 8; ++u)
                u8[u] = (p0 + u < QLEN) ? *(const unsigned short*)(rrow + p0 + u) : 0;
            rv0 = *(uint4*)u8;
        }
        int p1 = pn + (4 + wave) * 8;
        if (p1 + 7 < QLEN) rv1 = *(const uint4*)(rrow + p1);
        else {
            unsigned short u8[8];
#pragma unroll
            for (int u = 0; u < 8; ++u)
                u8[u] = (p1 + u < QLEN) ? *(const unsigned short*)(rrow + p1 + u) : 0;
            rv1 = *(uint4*)u8;
        }
    }
    __syncthreads(); // one-time full drain: Q/R staging visible

    const int qrow_off = (wave * 16 + l15) * 72 + quad * 8;
    bf16x8 qw0 = *(const bf16x8*)&Qrw[qrow_off];
    bf16x8 qw1 = *(const bf16x8*)&Qrw[qrow_off + 32];
    bf16x8 qr0 = *(const bf16x8*)&Qrr[qrow_off];
    bf16x8 qr1 = *(const bf16x8*)&Qrr[qrow_off + 32];

    // ---- pre-compute G lower half (cols [0,64) of first window) ----
    f32x4 g_acc[8];
#pragma unroll
    for (int nt = 0; nt < 4; ++nt) {
        f32x4 g = (f32x4){0.f, 0.f, 0.f, 0.f};
        int ro = (nt * 16 + l15) * 72 + quad * 8;
        bf16x8 b0 = *(const bf16x8*)&Rt[ro];
        bf16x8 b1 = *(const bf16x8*)&Rt[ro + 32];
        g = __builtin_amdgcn_mfma_f32_16x16x32_bf16(qr0, b0, g, 0, 0, 0);
        g = __builtin_amdgcn_mfma_f32_16x16x32_bf16(qr1, b1, g, 0, 0, 0);
        g_acc[nt] = g;
    }

    float l_r[4] = {0.f, 0.f, 0.f, 0.f};
    f32x4 o_acc[4];
#pragma unroll
    for (int dj = 0; dj < 4; ++dj) o_acc[dj] = (f32x4){0.f, 0.f, 0.f, 0.f};

    for (int jt = jt_lo; jt <= it; ++jt) {
        const int j0 = jt * 64;
        // (a) raw barrier: prior-phase LDS reads were consumed by MFMA/gather
        // lgkm-waits before any wave arrives; prefetch vmcnt rides through.
        asm volatile("" ::: "memory");
        __builtin_amdgcn_s_barrier();
        asm volatile("" ::: "memory");

        // ---- LDS writes from prefetched regs (compiler inserts counted
        //      vmcnt waits for the register consumption) ----
        {
            unsigned short u8[8];
            *(uint4*)u8 = kv0;
#pragma unroll
            for (int u = 0; u < 8; ++u) KtPs[(wave * 8 + u) * 72 + d_t] = u8[u];
            *(uint4*)u8 = kv1;
#pragma unroll
            for (int u = 0; u < 8; ++u) KtPs[((4 + wave) * 8 + u) * 72 + d_t] = u8[u];
            *(uint4*)&Vs[dv0 * 72 + jv0] = vv0;
            *(uint4*)&Vs[dv1 * 72 + jv0] = vv1;
            *(uint4*)u8 = rv0;
#pragma unroll
            for (int u = 0; u < 8; ++u) Rt[(wave * 8 + u) * 72 + d_t] = u8[u];
            *(uint4*)u8 = rv1;
#pragma unroll
            for (int u = 0; u < 8; ++u) Rt[((4 + wave) * 8 + u) * 72 + d_t] = u8[u];
        }

        // ---- prefetch NEXT tile: issued here, NOT drained by the barriers
        //      below; lands during AC/G/softmax/PV (~1-2k cyc of cover) ----
        if (jt < it) {
            const int j0n = j0 + 64;
            const bf16* krow = whb + (size_t)(1024 + hw + d_t) * QLEN + j0n;
            kv0 = *(const uint4*)(krow + wave * 8);
            kv1 = *(const uint4*)(krow + (4 + wave) * 8);
            vv0 = *(const uint4*)(whb + (size_t)(2048 + hw + dv0) * QLEN + j0n + jv0);
            vv1 = *(const uint4*)(whb + (size_t)(2048 + hw + dv1) * QLEN + j0n + jv0);
            const int pn = j0n - i0 + QLEN; // may exceed QLEN near the diagonal
            const bf16* rrow = rhk + (size_t)(hw + d_t) * QLEN;
            int p0 = pn + wave * 8;
            if (p0 + 7 < QLEN) rv0 = *(const uint4*)(rrow + p0);
            else {
                unsigned short u8[8];
#pragma unroll
                for (int u = 0; u < 8; ++u)
                    u8[u] = (p0 + u < QLEN) ? *(const unsigned short*)(rrow + p0 + u) : 0;
                rv0 = *(uint4*)u8;
            }
            int p1 = pn + (4 + wave) * 8;
            if (p1 + 7 < QLEN) rv1 = *(const uint4*)(rrow + p1);
            else {
                unsigned short u8[8];
#pragma unroll
                for (int u = 0; u < 8; ++u)
                    u8[u] = (p1 + u < QLEN) ? *(const unsigned short*)(rrow + p1 + u) : 0;
                rv1 = *(uint4*)u8;
            }
        }
        // (b) ds_writes visible to all waves; vmcnt deliberately NOT drained.
        asm volatile("s_waitcnt lgkmcnt(0)" ::: "memory");
        __builtin_amdgcn_s_barrier();
        asm volatile("" ::: "memory");

        // ---- AC MFMAs (8) ----
        f32x4 s_acc[4];
#pragma unroll
        for (int nj = 0; nj < 4; ++nj) {
            s_acc[nj] = (f32x4){0.f, 0.f, 0.f, 0.f};
            int ko = (nj * 16 + l15) * 72 + quad * 8;
            bf16x8 b0 = *(const bf16x8*)&KtPs[ko];
            bf16x8 b1 = *(const bf16x8*)&KtPs[ko + 32];
            s_acc[nj] = __builtin_amdgcn_mfma_f32_16x16x32_bf16(qw0, b0, s_acc[nj], 0, 0, 0);
            s_acc[nj] = __builtin_amdgcn_mfma_f32_16x16x32_bf16(qw1, b1, s_acc[nj], 0, 0, 0);
        }
        // ---- G upper-half MFMAs (8): window cols 64 + nt*16 + l15 ----
#pragma unroll
        for (int nt = 0; nt < 4; ++nt) {
            f32x4 g = (f32x4){0.f, 0.f, 0.f, 0.f};
            int ro = (nt * 16 + l15) * 72 + quad * 8;
            bf16x8 b0 = *(const bf16x8*)&Rt[ro];
            bf16x8 b1 = *(const bf16x8*)&Rt[ro + 32];
            g = __builtin_amdgcn_mfma_f32_16x16x32_bf16(qr0, b0, g, 0, 0, 0);
            g = __builtin_amdgcn_mfma_f32_16x16x32_bf16(qr1, b1, g, 0, 0, 0);
            g_acc[4 + nt] = g;
        }
        // (c) raw barrier: Kt/Rt reads (pinned by MFMA deps) complete before
        // the Gs overlay / Ps writes below; prefetch still in flight.
        asm volatile("" ::: "memory");
        __builtin_amdgcn_s_barrier();
        asm volatile("" ::: "memory");

        // ---- G writeback, t-major, b64-vectorized (wave-local i columns) ----
#pragma unroll
        for (int nt = 0; nt < 8; ++nt) {
            ushort4 u;
            u.x = f2bs(g_acc[nt][0]);
            u.y = f2bs(g_acc[nt][1]);
            u.z = f2bs(g_acc[nt][2]);
            u.w = f2bs(g_acc[nt][3]);
            *(ushort4*)&Gs[(nt * 16 + l15) * 76 + wave * 16 + quad * 4] = u;
        }

        // ---- gather BD + no-max softmax (Ps overlays Kt; wave-local) ----
        float rs[4] = {0.f, 0.f, 0.f, 0.f};
#pragma unroll
        for (int nj = 0; nj < 4; ++nj) {
#pragma unroll
            for (int r = 0; r < 4; ++r) {
                int i_loc = wave * 16 + quad * 4 + r;
                int j_loc = nj * 16 + l15;
                int t = j_loc - i_loc + 63; // in [0,126]
                float bd = bits2f(Gs[t * 76 + i_loc]);
                int diff = (i0 + i_loc) - (j0 + j_loc);
                float p = 0.f;
                if (diff >= 0 && diff < LOCAL_SIZE)
                    p = __expf((s_acc[nj][r] + bd) * 0.125f);
                KtPs[i_loc * 72 + j_loc] = f2bs(p);
                rs[r] += p;
            }
        }
#pragma unroll
        for (int r = 0; r < 4; ++r) {
            float v = rs[r];
            v += __shfl_xor(v, 1);
            v += __shfl_xor(v, 2);
            v += __shfl_xor(v, 4);
            v += __shfl_xor(v, 8);
            l_r[r] += v;
        }

        // ---- PV MFMAs (8) ----
        {
            int po = (wave * 16 + l15) * 72 + quad * 8;
            bf16x8 pa0 = *(const bf16x8*)&KtPs[po];
            bf16x8 pa1 = *(const bf16x8*)&KtPs[po + 32];
#pragma unroll
            for (int dj = 0; dj < 4; ++dj) {
                int vo = (dj * 16 + l15) * 72 + quad * 8;
                bf16x8 b0 = *(const bf16x8*)&Vs[vo];
                bf16x8 b1 = *(const bf16x8*)&Vs[vo + 32];
                o_acc[dj] = __builtin_amdgcn_mfma_f32_16x16x32_bf16(pa0, b0, o_acc[dj], 0, 0, 0);
                o_acc[dj] = __builtin_amdgcn_mfma_f32_16x16x32_bf16(pa1, b1, o_acc[dj], 0, 0, 0);
            }
        }

        // ---- shift G window: cols [64,128) become next iter's [0,64) ----
#pragma unroll
        for (int nt = 0; nt < 4; ++nt) g_acc[nt] = g_acc[nt + 4];
    }

    // ---- normalize and store (layout [b][q][h*64+d]) ----
#pragma unroll
    for (int r = 0; r < 4; ++r) {
        float inv = 1.f / l_r[r];
        int q = i0 + wave * 16 + quad * 4 + r;
        bf16* orow = av_out + ((size_t)b * QLEN + q) * D_MODEL + hw;
#pragma unroll
        for (int dj = 0; dj < 4; ++dj)
            orow[dj * 16 + l15] = __float2bfloat16(o_acc[dj][r] * inv);
    }
}

// ---------------------------------------------------------------------------
// Row LayerNorm in place (unchanged).
// ---------------------------------------------------------------------------
__global__ __launch_bounds__(256)
void ln_kernel(float* __restrict__ yt)
{
    const int b = blockIdx.y, q = blockIdx.x;
    float* row = yt + ((size_t)b * QLEN + q) * D_MODEL;
    const int t = threadIdx.x;
    float4 v = ((float4*)row)[t];
    float s  = v.x + v.y + v.z + v.w;
    float ss = v.x * v.x + v.y * v.y + v.z * v.z + v.w * v.w;
#pragma unroll
    for (int off = 32; off; off >>= 1) {
        s  += __shfl_down(s, off);
        ss += __shfl_down(ss, off);
    }
    __shared__ float sw[4], ssw[4];
    const int w = t >> 6;
    if ((t & 63) == 0) { sw[w] = s; ssw[w] = ss; }
    __syncthreads();
    float S  = sw[0] + sw[1] + sw[2] + sw[3];
    float SS = ssw[0] + ssw[1] + ssw[2] + ssw[3];
    float mu  = S / D_MODEL;
    float var = SS / D_MODEL - mu * mu;
    float rs  = rsqrtf(var + 1e-5f);
    v.x = (v.x - mu) * rs; v.y = (v.y - mu) * rs;
    v.z = (v.z - mu) * rs; v.w = (v.w - mu) * rs;
    ((float4*)row)[t] = v;
}

// ---------------------------------------------------------------------------
// Transpose y_t[b][q][o] fp32 -> out[b][o][q] (dtype per flag). Unchanged.
// ---------------------------------------------------------------------------
__global__ __launch_bounds__(256)
void transpose_out(const float* __restrict__ yt, void* __restrict__ out,
                   const int* __restrict__ flag)
{
    const int fl = *flag;
    const int b  = blockIdx.z;
    const int q0 = blockIdx.x * 32;
    const int o0 = blockIdx.y * 32;
    const int tx = threadIdx.x & 31, ty = threadIdx.x >> 5;
    __shared__ float T[32][33];
#pragma unroll
    for (int r = 0; r < 4; ++r) {
        int q = q0 + ty + r * 8;
        T[ty + r * 8][tx] = yt[((size_t)b * QLEN + q) * D_MODEL + o0 + tx];
    }
    __syncthreads();
#pragma unroll
    for (int r = 0; r < 4; ++r) {
        int o = o0 + ty + r * 8;
        size_t oi = ((size_t)b * D_MODEL + o) * QLEN + q0 + tx;
        float v = T[tx][ty + r * 8];
        if (fl) ((float*)out)[oi] = v;
        else    ((bf16*)out)[oi] = __float2bfloat16(v);
    }
}

// ---------------------------------------------------------------------------
extern "C" void kernel_launch(void* const* d_in, const int* in_sizes, int n_in,
                              void* d_out, int out_size, void* d_ws, size_t ws_size,
                              hipStream_t stream)
{
    const void* z1ss = d_in[0];
    const void* pos  = d_in[1];
    const void* u1ss = d_in[2];
    const void* Wqkv = d_in[3];
    const void* Wr   = d_in[4];
    const void* rwb  = d_in[5];
    const void* rrb  = d_in[6];
    const void* Wo   = d_in[7];
    const void* bo   = d_in[8];

    const size_t whE  = (size_t)BSZ * QKV3 * QLEN;     // 12,582,912 elems
    const size_t rhkE = (size_t)D_MODEL * QLEN;        //  2,097,152
    const size_t avE  = (size_t)BSZ * QLEN * D_MODEL;  //  4,194,304
    const size_t ztE  = avE;
    const size_t wqE  = (size_t)QKV3 * D_MODEL;        //  3,145,728
    const size_t wrE  = (size_t)D_MODEL * D_MODEL;     //  1,048,576
    const size_t woE  = wrE;

    char* ws = (char*)d_ws;
    bf16* wh   = (bf16*)ws;            // [B][3072][Q] o-major (q|k|v)
    bf16* rhk  = wh + whE;             // [1024][Q] o-major
    bf16* avec = rhk + rhkE;           // [B][Q][1024]
    bf16* post = avec;                 // overlay: dead before attn writes avec
    size_t baseB = (whE + rhkE + avE) * sizeof(bf16);
    bf16* zt  = (bf16*)(ws + baseB);
    bf16* wqb = zt + ztE;              // wqb|wrb|wob contiguous (convw_all)
    bf16* wrb = wqb + wqE;
    bf16* wob = wrb + wrE;
    float* yt = (float*)ws;            // overlays wh (dead after attn)

    const size_t t2B = baseB + ztE * sizeof(bf16) + 16;
    const size_t t1B = baseB + (ztE + wqE + wrE + woE) * sizeof(bf16) + 16;
    const int tier = (ws_size >= t1B) ? 1 : (ws_size >= t2B) ? 2 : 3;

    int* flag = (tier == 1) ? (int*)(wob + woE)
              : (tier == 2) ? (int*)(wqb)
                            : (int*)(ws + baseB);

    detect_kernel<<<1, 64, 0, stream>>>((const unsigned short*)Wqkv, flag);

    if (tier == 1) {
        // 0a. weights -> bf16 (one dispatch; outputs contiguous)
        convw_all<<<dim3((unsigned)((wqE + wrE + woE) / 2048)), 256, 0, stream>>>(
            Wqkv, Wr, Wo, wqb, flag);

        // 0b. transposes (one dispatch: z in [0,BSZ] with z==BSZ -> pos)
        tcvt_all<<<dim3(QLEN / 32, D_MODEL / 32, BSZ + 1), 256, 0, stream>>>(
            z1ss, pos, zt, post, flag);

        // 1+2. fused QKV + rhk GEMM
        gemm_qkvr<<<dim3(QLEN / 128, QKV3 / 128 + D_MODEL / 128, BSZ), 256, 0, stream>>>(
            wqb, wrb, zt, post, wh, rhk, u1ss, flag);

        // 3. MFMA banded flash attention v7 -> avec[b][q][1024]
        attn_mfma<<<dim3(QLEN / 64, N_HEAD, BSZ), 256, 0, stream>>>(
            wh, rhk, rwb, rrb, avec, flag);

        // 4. y_t[b][q][o] = avec . Wo^T + bo + zt
        gemm_glds<<<dim3(1024 / 128, 2048 / 128, BSZ), 256, 0, stream>>>(
            avec, (size_t)QLEN * D_MODEL,
            wob, 0,
            yt, 0, (size_t)QLEN * D_MODEL,
            zt, 0, (size_t)QLEN * D_MODEL,
            bo, 2,
            QLEN, D_MODEL, D_MODEL, flag);
    } else if (tier == 2) {
        // proven round-2 path
        tcvt_all<<<dim3(QLEN / 32, D_MODEL / 32, BSZ + 1), 256, 0, stream>>>(
            z1ss, pos, zt, post, flag);

        gemm_bf16<<<dim3(2048 / 128, 3072 / 128, BSZ), 256, 0, stream>>>(
            Wqkv, 2, 0,
            zt, 0, (size_t)QLEN * D_MODEL,
            wh, 1, (size_t)QKV3 * QLEN,
            u1ss, 2, (size_t)QKV3 * QLEN,
            nullptr, 0,
            QKV3, QLEN, D_MODEL, flag);

        gemm_bf16<<<dim3(2048 / 128, 1024 / 128, 1), 256, 0, stream>>>(
            Wr, 2, 0,
            post, 0, 0,
            rhk, 1, 0,
            nullptr, 0, 0,
            nullptr, 0,
            D_MODEL, QLEN, D_MODEL, flag);

        attn_mfma<<<dim3(QLEN / 64, N_HEAD, BSZ), 256, 0, stream>>>(
            wh, rhk, rwb, rrb, avec, flag);

        gemm_bf16<<<dim3(1024 / 128, 2048 / 128, BSZ), 256, 0, stream>>>(
            avec, 0, (size_t)QLEN * D_MODEL,
            Wo, 2, 0,
            yt, 0, (size_t)QLEN * D_MODEL,
            zt, 0, (size_t)QLEN * D_MODEL,
            bo, 2,
            QLEN, D_MODEL, D_MODEL, flag);
    } else {
        // fallback: proven gemm_tn path (in-GEMM transpose) + attn
        gemm_tn<<<dim3(2048 / 128, 3072 / 128, BSZ), 256, 0, stream>>>(
            Wqkv, 2, 0,
            z1ss, 2, 1, QLEN, (size_t)D_MODEL * QLEN,
            wh, 1, (size_t)QKV3 * QLEN,
            u1ss, 2, 0, (size_t)QKV3 * QLEN,
            nullptr, 0,
            QKV3, QLEN, D_MODEL, flag);
        gemm_tn<<<dim3(2048 / 128, 1024 / 128, 1), 256, 0, stream>>>(
            Wr, 2, 0,
            pos, 2, 1, QLEN, 0,
            rhk, 1, 0,
            nullptr, 0, 0, 0,
            nullptr, 0,
            D_MODEL, QLEN, D_MODEL, flag);
        attn_mfma<<<dim3(QLEN / 64, N_HEAD, BSZ), 256, 0, stream>>>(
            wh, rhk, rwb, rrb, avec, flag);
        gemm_tn<<<dim3(1024 / 128, 2048 / 128, BSZ), 256, 0, stream>>>(
            avec, 0, (size_t)QLEN * D_MODEL,
            Wo, 2, 0, D_MODEL, 0,
            yt, 0, (size_t)QLEN * D_MODEL,
            z1ss, 2, 1, (size_t)D_MODEL * QLEN,
            bo, 2,
            QLEN, D_MODEL, D_MODEL, flag);
    }

    // 5. LN in place on y_t rows
    ln_kernel<<<dim3(QLEN, BSZ), 256, 0, stream>>>(yt);

    // 6. transpose to out[b][o][q]
    transpose_out<<<dim3(QLEN / 32, D_MODEL / 32, BSZ), 256, 0, stream>>>(yt, d_out, flag);
}

// Round 7
// 405.932 us; speedup vs baseline: 1.0182x; 1.0182x over previous
//
#include <hip/hip_runtime.h>
#include <hip/hip_bf16.h>

#define D_MODEL 1024
#define N_HEAD 16
#define BSZ 2
#define QLEN 2048
#define LOCAL_SIZE 1000
#define QKV3 (3 * N_HEAD * 64) // 3072

typedef __hip_bfloat16 bf16;
typedef short bf16x8 __attribute__((ext_vector_type(8)));
typedef float f32x4 __attribute__((ext_vector_type(4)));

static __device__ __forceinline__ float b2f(bf16 x) { return __bfloat162float(x); }
static __device__ __forceinline__ float bits2f(unsigned short u) {
    return __uint_as_float(((unsigned int)u) << 16);
}
static __device__ __forceinline__ unsigned short f2bs(float x) {
    __hip_bfloat16 h = __float2bfloat16(x);
    return *(unsigned short*)&h;
}

// mode: 0 = always bf16, 1 = always fp32, 2 = follow runtime flag (raw harness tensor)
static __device__ __forceinline__ int rmode(int m, int fl) { return (m == 2) ? fl : m; }
static __device__ __forceinline__ float ldm(const void* p, size_t i, int isf) {
    return isf ? ((const float*)p)[i] : b2f(((const bf16*)p)[i]);
}
static __device__ __forceinline__ float4 ld4(const void* p, size_t i, int isf) {
    if (isf) return ((const float4*)p)[i >> 2];
    ushort4 u = ((const ushort4*)p)[i >> 2];
    float4 f;
    f.x = bits2f(u.x); f.y = bits2f(u.y); f.z = bits2f(u.z); f.w = bits2f(u.w);
    return f;
}
static __device__ __forceinline__ ushort4 cvt4(float4 f) {
    ushort4 u;
    u.x = f2bs(f.x); u.y = f2bs(f.y); u.z = f2bs(f.z); u.w = f2bs(f.w);
    return u;
}

// async global->LDS, 16 B per lane; LDS dest = wave-uniform base + lane*16
static __device__ __forceinline__ void glds16(const bf16* g, unsigned short* l) {
    __builtin_amdgcn_global_load_lds(
        (const __attribute__((address_space(1))) void*)g,
        (__attribute__((address_space(3))) void*)l,
        16, 0, 0);
}

// ---------------------------------------------------------------------------
// dtype detector (flag: 0 = bf16 data, 1 = fp32 data). Proven.
// ---------------------------------------------------------------------------
__global__ void detect_kernel(const unsigned short* __restrict__ w, int* __restrict__ flag)
{
    if (threadIdx.x == 0 && blockIdx.x == 0) {
        int good = 0;
        for (int i = 0; i < 256; ++i) {
            float v = bits2f(w[i]);
            if (v == v && fabsf(v) < 8.0f) ++good;
        }
        *flag = (good >= 240) ? 0 : 1;
    }
}

// ---------------------------------------------------------------------------
// Fused weight convert: Wqkv|Wr|Wo (raw) -> contiguous bf16 at wqb.
// ---------------------------------------------------------------------------
__global__ __launch_bounds__(256)
void convw_all(const void* __restrict__ wq, const void* __restrict__ wr,
               const void* __restrict__ wo, bf16* __restrict__ outp,
               const int* __restrict__ flag)
{
    const int fl = *flag;
    const int blk = blockIdx.x;
    const void* in; size_t segOff;
    if (blk < 1536)      { in = wq; segOff = (size_t)blk * 2048; }
    else if (blk < 2048) { in = wr; segOff = (size_t)(blk - 1536) * 2048; }
    else                 { in = wo; segOff = (size_t)(blk - 2048) * 2048; }
    const size_t ii = segOff + (size_t)threadIdx.x * 8;
    const size_t oi = (size_t)blk * 2048 + (size_t)threadIdx.x * 8;
    if (fl) {
        float4 a = ((const float4*)in)[ii / 4];
        float4 b = ((const float4*)in)[ii / 4 + 1];
        *(ushort4*)((unsigned short*)outp + oi)     = cvt4(a);
        *(ushort4*)((unsigned short*)outp + oi + 4) = cvt4(b);
    } else {
        *(uint4*)((unsigned short*)outp + oi) = ((const uint4*)in)[ii / 8];
    }
}

// ---------------------------------------------------------------------------
// Fused transpose+convert: z1ss (z<BSZ) and pos (z==BSZ) -> [q][d] bf16.
// ---------------------------------------------------------------------------
__global__ __launch_bounds__(256)
void tcvt_all(const void* __restrict__ z1ss, const void* __restrict__ pos,
              bf16* __restrict__ zt, bf16* __restrict__ post,
              const int* __restrict__ flag)
{
    const int fl = *flag;
    const int zb = blockIdx.z;
    const void* in = (zb < BSZ) ? z1ss : pos;
    const size_t inOff = (zb < BSZ) ? (size_t)zb * D_MODEL * QLEN : 0;
    bf16* outp = (zb < BSZ) ? zt + (size_t)zb * QLEN * D_MODEL : post;
    const int c0 = blockIdx.x * 32;   // col (q) in [0, QLEN)
    const int r0 = blockIdx.y * 32;   // row (d) in [0, D_MODEL)
    const int tx = threadIdx.x & 31, ty = threadIdx.x >> 5;
    __shared__ float T[32][33];
#pragma unroll
    for (int r = 0; r < 4; ++r) {
        int rr = r0 + ty + r * 8;
        T[ty + r * 8][tx] = ldm(in, inOff + (size_t)rr * QLEN + c0 + tx, fl);
    }
    __syncthreads();
#pragma unroll
    for (int r = 0; r < 4; ++r) {
        int cc = c0 + ty + r * 8;
        outp[(size_t)cc * D_MODEL + r0 + tx] = __float2bfloat16(T[tx][ty + r * 8]);
    }
}

// ---------------------------------------------------------------------------
// Fused QKV + rhk GEMM, glds-staged (proven structure from round 3).
// ---------------------------------------------------------------------------
__global__ __launch_bounds__(256)
void gemm_qkvr(const bf16* __restrict__ wqb, const bf16* __restrict__ wrb,
               const bf16* __restrict__ zt, const bf16* __restrict__ post,
               bf16* __restrict__ wh, bf16* __restrict__ rhk,
               const void* __restrict__ u1ss, const int* __restrict__ flag)
{
    const int fl = *flag;
    const int bz = blockIdx.z;
    const int by = blockIdx.y;
    const bool isR = by >= (QKV3 / 128);
    if (isR && bz) return;
    const int n0 = blockIdx.x * 128;
    const int m0 = (isR ? by - QKV3 / 128 : by) * 128;
    const int K = D_MODEL, N = QLEN;

    const bf16* A = isR ? wrb : wqb;
    const bf16* B = isR ? post : zt + (size_t)bz * (size_t)QLEN * D_MODEL;
    bf16* C       = isR ? rhk  : wh + (size_t)bz * (size_t)QKV3 * QLEN;
    const size_t uOff = (size_t)bz * (size_t)QKV3 * QLEN;

    const int tid = threadIdx.x;
    const int wave = tid >> 6, lane = tid & 63;
    const int quad = lane >> 4, l15 = lane & 15;
    const int wm = (wave >> 1) * 64, wn = (wave & 1) * 64;

    __shared__ __align__(16) unsigned short A_s[2][128 * 32];
    __shared__ __align__(16) unsigned short B_s[2][128 * 32];

    const int srow = wave * 32 + (lane >> 2);
    const int scol = (lane & 3) * 8;
    const bf16* Ag = A + (size_t)(m0 + srow) * K + scol;
    const bf16* Bg = B + (size_t)(n0 + srow) * K + scol;
    const int sbase = wave * 1024;

    f32x4 acc[4][4];
#pragma unroll
    for (int i = 0; i < 4; ++i)
#pragma unroll
        for (int j = 0; j < 4; ++j) acc[i][j] = (f32x4){0.f, 0.f, 0.f, 0.f};

    glds16(Ag,                   &A_s[0][sbase]);
    glds16(Ag + (size_t)16 * K,  &A_s[0][sbase + 512]);
    glds16(Bg,                   &B_s[0][sbase]);
    glds16(Bg + (size_t)16 * K,  &B_s[0][sbase + 512]);

    int cur = 0;
    for (int k0 = 0; k0 < K; k0 += 32) {
        __syncthreads();
        if (k0 + 32 < K) {
            const int kn = k0 + 32;
            glds16(Ag + kn,                  &A_s[cur ^ 1][sbase]);
            glds16(Ag + (size_t)16 * K + kn, &A_s[cur ^ 1][sbase + 512]);
            glds16(Bg + kn,                  &B_s[cur ^ 1][sbase]);
            glds16(Bg + (size_t)16 * K + kn, &B_s[cur ^ 1][sbase + 512]);
        }
        bf16x8 a[4], bb[4];
#pragma unroll
        for (int i = 0; i < 4; ++i)
            a[i] = *(const bf16x8*)&A_s[cur][(wm + i * 16 + l15) * 32 + quad * 8];
#pragma unroll
        for (int j = 0; j < 4; ++j)
            bb[j] = *(const bf16x8*)&B_s[cur][(wn + j * 16 + l15) * 32 + quad * 8];
#pragma unroll
        for (int i = 0; i < 4; ++i)
#pragma unroll
            for (int j = 0; j < 4; ++j)
                acc[i][j] = __builtin_amdgcn_mfma_f32_16x16x32_bf16(a[i], bb[j], acc[i][j], 0, 0, 0);
        cur ^= 1;
    }

#pragma unroll
    for (int i = 0; i < 4; ++i) {
#pragma unroll
        for (int j = 0; j < 4; ++j) {
            int n = n0 + wn + j * 16 + l15;
#pragma unroll
            for (int r = 0; r < 4; ++r) {
                int m = m0 + wm + i * 16 + quad * 4 + r;
                float v = acc[i][j][r];
                if (!isR) v += ldm(u1ss, uOff + (size_t)m * N + n, fl);
                C[(size_t)m * N + n] = __float2bfloat16(v);
            }
        }
    }
}

// ---------------------------------------------------------------------------
// m97-style GEMM: global_load_lds staging, double-buffered LDS (round-3 proven).
// ---------------------------------------------------------------------------
__global__ __launch_bounds__(256)
void gemm_glds(const bf16* __restrict__ A, size_t sAb,
               const bf16* __restrict__ B, size_t sBb,
               void* __restrict__ C, int c_is_bf16, size_t sCb,
               const void* __restrict__ addm, int mAdd, size_t sAddb,
               const void* __restrict__ bias, int mBias,
               int M, int N, int K, const int* __restrict__ flag)
{
    const int fl = *flag;
    const int fAdd = rmode(mAdd, fl), fBias = rmode(mBias, fl);

    const int bz = blockIdx.z;
    const int n0 = blockIdx.x * 128;
    const int m0 = blockIdx.y * 128;
    const int tid = threadIdx.x;
    const int wave = tid >> 6, lane = tid & 63;
    const int quad = lane >> 4, l15 = lane & 15;
    const int wm = (wave >> 1) * 64, wn = (wave & 1) * 64;

    __shared__ __align__(16) unsigned short A_s[2][128 * 32];
    __shared__ __align__(16) unsigned short B_s[2][128 * 32];

    const int srow = wave * 32 + (lane >> 2);
    const int scol = (lane & 3) * 8;
    const bf16* Ag = A + (size_t)bz * sAb + (size_t)(m0 + srow) * K + scol;
    const bf16* Bg = B + (size_t)bz * sBb + (size_t)(n0 + srow) * K + scol;
    const int sbase = wave * 1024;

    f32x4 acc[4][4];
#pragma unroll
    for (int i = 0; i < 4; ++i)
#pragma unroll
        for (int j = 0; j < 4; ++j) acc[i][j] = (f32x4){0.f, 0.f, 0.f, 0.f};

    glds16(Ag,                   &A_s[0][sbase]);
    glds16(Ag + (size_t)16 * K,  &A_s[0][sbase + 512]);
    glds16(Bg,                   &B_s[0][sbase]);
    glds16(Bg + (size_t)16 * K,  &B_s[0][sbase + 512]);

    int cur = 0;
    for (int k0 = 0; k0 < K; k0 += 32) {
        __syncthreads();
        if (k0 + 32 < K) {
            const int kn = k0 + 32;
            glds16(Ag + kn,                  &A_s[cur ^ 1][sbase]);
            glds16(Ag + (size_t)16 * K + kn, &A_s[cur ^ 1][sbase + 512]);
            glds16(Bg + kn,                  &B_s[cur ^ 1][sbase]);
            glds16(Bg + (size_t)16 * K + kn, &B_s[cur ^ 1][sbase + 512]);
        }
        bf16x8 a[4], bb[4];
#pragma unroll
        for (int i = 0; i < 4; ++i)
            a[i] = *(const bf16x8*)&A_s[cur][(wm + i * 16 + l15) * 32 + quad * 8];
#pragma unroll
        for (int j = 0; j < 4; ++j)
            bb[j] = *(const bf16x8*)&B_s[cur][(wn + j * 16 + l15) * 32 + quad * 8];
#pragma unroll
        for (int i = 0; i < 4; ++i)
#pragma unroll
            for (int j = 0; j < 4; ++j)
                acc[i][j] = __builtin_amdgcn_mfma_f32_16x16x32_bf16(a[i], bb[j], acc[i][j], 0, 0, 0);
        cur ^= 1;
    }

    const size_t cb = (size_t)bz * sCb;
#pragma unroll
    for (int i = 0; i < 4; ++i) {
#pragma unroll
        for (int j = 0; j < 4; ++j) {
            int n = n0 + wn + j * 16 + l15;
#pragma unroll
            for (int r = 0; r < 4; ++r) {
                int m = m0 + wm + i * 16 + quad * 4 + r;
                float v = acc[i][j][r];
                if (addm) v += ldm(addm, (size_t)bz * sAddb + (size_t)m * N + n, fAdd);
                if (bias) v += ldm(bias, (size_t)n, fBias);
                size_t ci = cb + (size_t)m * N + n;
                if (c_is_bf16) ((bf16*)C)[ci] = __float2bfloat16(v);
                else           ((float*)C)[ci] = v;
            }
        }
    }
}

// ---------------------------------------------------------------------------
// Software-pipelined MFMA TN-GEMM (tier-2 fallback, proven).
// ---------------------------------------------------------------------------
__global__ __launch_bounds__(256)
void gemm_bf16(const void* __restrict__ A, int mA, size_t sAb,
               const void* __restrict__ B, int mB, size_t sBb,
               void* __restrict__ C, int c_is_bf16, size_t sCb,
               const void* __restrict__ addm, int mAdd, size_t sAddb,
               const void* __restrict__ bias, int mBias,
               int M, int N, int K, const int* __restrict__ flag)
{
    const int fl = *flag;
    const int fA = rmode(mA, fl), fB = rmode(mB, fl);
    const int fAdd = rmode(mAdd, fl), fBias = rmode(mBias, fl);

    const int bz = blockIdx.z;
    const int n0 = blockIdx.x * 128;
    const int m0 = blockIdx.y * 128;
    const int tid = threadIdx.x;
    const int wave = tid >> 6, lane = tid & 63;
    const int quad = lane >> 4, l15 = lane & 15;
    const int wm = (wave >> 1) * 64, wn = (wave & 1) * 64;

    __shared__ unsigned short A_s[128][40];
    __shared__ unsigned short B_s[128][40];

    const int r0c = tid >> 2,         c0c = tid & 3;
    const int r1c = (tid + 256) >> 2, c1c = tid & 3;

    const size_t aOff = (size_t)bz * sAb;
    const size_t bOff = (size_t)bz * sBb;
    const bf16*  Ah = (const bf16*)A;
    const float* Af = (const float*)A;
    const bf16*  Bh = (const bf16*)B;
    const float* Bf = (const float*)B;

    uint4 pa[4], pb[4];

#define LOAD_OP(p, fX, Xh, Xf, xOff, R0, C0, R1, C1, base, k0)                          \
    do {                                                                                \
        if (!fX) {                                                                      \
            p[0] = *(const uint4*)(Xh + xOff + (size_t)(base + R0) * K + (k0) + C0 * 8);\
            p[1] = *(const uint4*)(Xh + xOff + (size_t)(base + R1) * K + (k0) + C1 * 8);\
        } else {                                                                        \
            const float* q0 = Xf + xOff + (size_t)(base + R0) * K + (k0) + C0 * 8;      \
            const float* q1 = Xf + xOff + (size_t)(base + R1) * K + (k0) + C1 * 8;      \
            p[0] = *(const uint4*)q0; p[1] = *(const uint4*)(q0 + 4);                   \
            p[2] = *(const uint4*)q1; p[3] = *(const uint4*)(q1 + 4);                   \
        }                                                                               \
    } while (0)

#define WRITE_OP(p, fX, S, R0, C0, R1, C1)                                              \
    do {                                                                                \
        if (!fX) {                                                                      \
            *(uint4*)&S[R0][C0 * 8] = p[0];                                             \
            *(uint4*)&S[R1][C1 * 8] = p[1];                                             \
        } else {                                                                        \
            float4 f0 = *(float4*)&p[0], f1 = *(float4*)&p[1];                          \
            float4 f2 = *(float4*)&p[2], f3 = *(float4*)&p[3];                          \
            *(ushort4*)&S[R0][C0 * 8]     = cvt4(f0);                                   \
            *(ushort4*)&S[R0][C0 * 8 + 4] = cvt4(f1);                                   \
            *(ushort4*)&S[R1][C1 * 8]     = cvt4(f2);                                   \
            *(ushort4*)&S[R1][C1 * 8 + 4] = cvt4(f3);                                   \
        }                                                                               \
    } while (0)

    f32x4 acc[4][4];
#pragma unroll
    for (int i = 0; i < 4; ++i)
#pragma unroll
        for (int j = 0; j < 4; ++j) acc[i][j] = (f32x4){0.f, 0.f, 0.f, 0.f};

    LOAD_OP(pa, fA, Ah, Af, aOff, r0c, c0c, r1c, c1c, m0, 0);
    LOAD_OP(pb, fB, Bh, Bf, bOff, r0c, c0c, r1c, c1c, n0, 0);

    for (int k0 = 0; k0 < K; k0 += 32) {
        WRITE_OP(pa, fA, A_s, r0c, c0c, r1c, c1c);
        WRITE_OP(pb, fB, B_s, r0c, c0c, r1c, c1c);
        __syncthreads();

        const int kn = k0 + 32;
        if (kn < K) {
            LOAD_OP(pa, fA, Ah, Af, aOff, r0c, c0c, r1c, c1c, m0, kn);
            LOAD_OP(pb, fB, Bh, Bf, bOff, r0c, c0c, r1c, c1c, n0, kn);
        }

        bf16x8 a[4], bb[4];
#pragma unroll
        for (int i = 0; i < 4; ++i)
            a[i] = *(const bf16x8*)&A_s[wm + i * 16 + l15][quad * 8];
#pragma unroll
        for (int j = 0; j < 4; ++j)
            bb[j] = *(const bf16x8*)&B_s[wn + j * 16 + l15][quad * 8];
#pragma unroll
        for (int i = 0; i < 4; ++i)
#pragma unroll
            for (int j = 0; j < 4; ++j)
                acc[i][j] = __builtin_amdgcn_mfma_f32_16x16x32_bf16(a[i], bb[j], acc[i][j], 0, 0, 0);
        __syncthreads();
    }
#undef LOAD_OP
#undef WRITE_OP

    const size_t cb = (size_t)bz * sCb;
#pragma unroll
    for (int i = 0; i < 4; ++i) {
#pragma unroll
        for (int j = 0; j < 4; ++j) {
            int n = n0 + wn + j * 16 + l15;
#pragma unroll
            for (int r = 0; r < 4; ++r) {
                int m = m0 + wm + i * 16 + quad * 4 + r;
                float v = acc[i][j][r];
                if (addm) v += ldm(addm, (size_t)bz * sAddb + (size_t)m * N + n, fAdd);
                if (bias) v += ldm(bias, (size_t)n, fBias);
                size_t ci = cb + (size_t)m * N + n;
                if (c_is_bf16) ((bf16*)C)[ci] = __float2bfloat16(v);
                else           ((float*)C)[ci] = v;
            }
        }
    }
}

// ---------------------------------------------------------------------------
// Old MFMA TN-GEMM (small-workspace fallback only).
// ---------------------------------------------------------------------------
__global__ __launch_bounds__(256)
void gemm_tn(const void* __restrict__ A, int mA, size_t sAb,
             const void* __restrict__ Bsrc, int mB, int bTrans, int ldB, size_t sBb,
             void* __restrict__ C, int c_is_bf16, size_t sCb,
             const void* __restrict__ addm, int mAdd, int addT, size_t sAddb,
             const void* __restrict__ bias, int mBias,
             int M, int N, int K, const int* __restrict__ flag)
{
    const int fl = *flag;
    const int fA = rmode(mA, fl), fB = rmode(mB, fl);
    const int fAdd = rmode(mAdd, fl), fBias = rmode(mBias, fl);

    const int bz = blockIdx.z;
    const int n0 = blockIdx.x * 128;
    const int m0 = blockIdx.y * 128;
    const int tid = threadIdx.x;
    const int wave = tid >> 6, lane = tid & 63;
    const int quad = lane >> 4, l15 = lane & 15;
    const int wm = (wave >> 1) * 64, wn = (wave & 1) * 64;

    __shared__ unsigned short A_s[128][40];
    __shared__ unsigned short B_s[128][40];

    const size_t aBase = (size_t)bz * sAb;
    const size_t bBase = (size_t)bz * sBb;

    f32x4 acc[4][4];
#pragma unroll
    for (int i = 0; i < 4; ++i)
#pragma unroll
        for (int j = 0; j < 4; ++j) acc[i][j] = (f32x4){0.f, 0.f, 0.f, 0.f};

    for (int k0 = 0; k0 < K; k0 += 32) {
#pragma unroll
        for (int g = 0; g < 4; ++g) {
            int c = tid + g * 256;
            int m = c >> 3, kc = (c & 7) * 4;
            float4 f = ld4(A, aBase + (size_t)(m0 + m) * K + k0 + kc, fA);
            *(ushort4*)&A_s[m][kc] = cvt4(f);
        }
        if (!bTrans) {
#pragma unroll
            for (int g = 0; g < 4; ++g) {
                int c = tid + g * 256;
                int n = c >> 3, kc = (c & 7) * 4;
                float4 f = ld4(Bsrc, bBase + (size_t)(n0 + n) * ldB + k0 + kc, fB);
                *(ushort4*)&B_s[n][kc] = cvt4(f);
            }
        } else {
#pragma unroll
            for (int g = 0; g < 4; ++g) {
                int c = tid + g * 256;
                int k = c >> 5, nc = (c & 31) * 4;
                float4 f = ld4(Bsrc, bBase + (size_t)(k0 + k) * ldB + n0 + nc, fB);
                ushort4 u = cvt4(f);
                B_s[nc + 0][k] = u.x;
                B_s[nc + 1][k] = u.y;
                B_s[nc + 2][k] = u.z;
                B_s[nc + 3][k] = u.w;
            }
        }
        __syncthreads();

        bf16x8 a[4], bb[4];
#pragma unroll
        for (int i = 0; i < 4; ++i)
            a[i] = *(const bf16x8*)&A_s[wm + i * 16 + l15][quad * 8];
#pragma unroll
        for (int j = 0; j < 4; ++j)
            bb[j] = *(const bf16x8*)&B_s[wn + j * 16 + l15][quad * 8];
#pragma unroll
        for (int i = 0; i < 4; ++i)
#pragma unroll
            for (int j = 0; j < 4; ++j)
                acc[i][j] = __builtin_amdgcn_mfma_f32_16x16x32_bf16(a[i], bb[j], acc[i][j], 0, 0, 0);
        __syncthreads();
    }

    const size_t cb = (size_t)bz * sCb;
#pragma unroll
    for (int i = 0; i < 4; ++i) {
#pragma unroll
        for (int j = 0; j < 4; ++j) {
            int n = n0 + wn + j * 16 + l15;
#pragma unroll
            for (int r = 0; r < 4; ++r) {
                int m = m0 + wm + i * 16 + quad * 4 + r;
                float v = acc[i][j][r];
                if (addm) {
                    size_t ai = (size_t)bz * sAddb +
                                (addT ? ((size_t)n * M + m) : ((size_t)m * N + n));
                    v += ldm(addm, ai, fAdd);
                }
                if (bias) v += ldm(bias, (size_t)n, fBias);
                size_t ci = cb + (size_t)m * N + n;
                if (c_is_bf16) ((bf16*)C)[ci] = __float2bfloat16(v);
                else           ((float*)C)[ci] = v;
            }
        }
    }
}

// ---------------------------------------------------------------------------
// MFMA banded flash attention v8:
//  Round-6 analysis: 7.18M bank conflicts/dispatch = 550 cyc/iter, located in
//  the Gs diagonal gather (scalar reads on a 16-even-bank lattice = 4-way).
//  The entire Gs roundtrip is WAVE-LOCAL, so:
//   1. Gs writeback + gather replaced by ds_bpermute redistribution:
//      source lane = (lane&48)|((l15-4q-r-1)&15), source reg n0 = 3-wave+nj,
//      2-candidate select with cond l15 > 4*quad + r (wave/nj-independent).
//      bd stays f32 (skips the bf16 roundtrip). Wave-uniform branch keeps
//      g_acc indexing compile-time (rule #20).
//   2. Ps gets its own buffer (freed Gs space) -> barrier (c) removed:
//      2 barriers/iter. All cross-wave LDS (Kt/Vs/Rt) written in [bar a, bar b],
//      read in [bar b, next bar a]; Ps is wave-local.
//   3. Work-balance it-permutation: co-resident blocks {l, l+256, l+512, l+768}
//      previously shared the same it (per-CU load 4..68 iters). Remap so each
//      CU-set has lengths {17,17,p+1,16-p} = 51.
// ---------------------------------------------------------------------------
__global__ __launch_bounds__(256)
void attn_mfma(const bf16* __restrict__ wh,  // [B][3072][Q]
               const bf16* __restrict__ rhk, // [1024][Q]
               const void* __restrict__ rwb, // [1024] raw
               const void* __restrict__ rrb, // [1024] raw
               bf16* __restrict__ av_out,    // [B][Q][1024]
               const int* __restrict__ flag)
{
    const int fl = *flag;
    // ---- work-balance decode: slot s gets it in {16+p, 24+p, p, 15-p} ----
    const int lidx = blockIdx.x + 32 * (blockIdx.y + (blockIdx.z << 4)); // [0,1024)
    const int slot = lidx >> 8;
    const int grp  = lidx & 255;
    const int hb   = grp & 31;
    const int prm  = grp >> 5; // [0,8)
    const int it   = (slot == 0) ? 16 + prm : (slot == 1) ? 24 + prm
                   : (slot == 2) ? prm : 15 - prm;
    const int h = hb & 15, b = hb >> 4;

    const int i0 = it * 64;
    const int tid = threadIdx.x;
    const int wave = tid >> 6, lane = tid & 63;
    const int quad = lane >> 4, l15 = lane & 15;
    const int hw = h * 64;

    __shared__ __align__(16) unsigned short sm[18432]; // 36,864 B -> 4 blocks/CU
    unsigned short* Kt  = sm;           // [64][72]  K^T tile [j][d]
    unsigned short* Vs  = sm + 4608;    // [64][72]  V tile [d][j]
    unsigned short* Rt  = sm + 9216;    // [64][72]  new R half [t][d]
    unsigned short* Ps  = sm + 13824;   // [64][72]  P (own buffer, wave-local)
    unsigned short* Qrw = sm;           // init-only overlay
    unsigned short* Qrr = sm + 4608;    // init-only overlay

    const bf16* whb = wh + (size_t)b * QKV3 * QLEN;
    const int d_t = tid & 63;
    const int dv0 = tid >> 3, jv0 = (tid & 7) * 8;
    const int dv1 = (tid + 256) >> 3;

    int lo = i0 - (LOCAL_SIZE - 1);
    if (lo < 0) lo = 0;
    const int jt_lo = lo >> 6;
    const int j0_lo = jt_lo * 64;

    // ---- stage Q (+biases) and initial R lower half; all loads first ----
    {
        float brw = ldm(rwb, hw + d_t, fl);
        float brr = ldm(rrb, hw + d_t, fl);
        const bf16* qrow = whb + (size_t)(hw + d_t) * QLEN + i0;
        uint4 qv0 = *(const uint4*)(qrow + wave * 8);
        uint4 qv1 = *(const uint4*)(qrow + (4 + wave) * 8);
        // initial window cols t in [0,64): p = pbase0 + t; provably in [922,2047]
        const int pbase0 = j0_lo - i0 + QLEN - 64;
        const bf16* rrow = rhk + (size_t)(hw + d_t) * QLEN;
        uint4 rv0i = *(const uint4*)(rrow + pbase0 + wave * 8);
        uint4 rv1i = *(const uint4*)(rrow + pbase0 + (4 + wave) * 8);

        unsigned short u8[8];
        *(uint4*)u8 = qv0;
#pragma unroll
        for (int u = 0; u < 8; ++u) {
            float q = bits2f(u8[u]);
            Qrw[(wave * 8 + u) * 72 + d_t] = f2bs(q + brw);
            Qrr[(wave * 8 + u) * 72 + d_t] = f2bs(q + brr);
        }
        *(uint4*)u8 = qv1;
#pragma unroll
        for (int u = 0; u < 8; ++u) {
            float q = bits2f(u8[u]);
            Qrw[((4 + wave) * 8 + u) * 72 + d_t] = f2bs(q + brw);
            Qrr[((4 + wave) * 8 + u) * 72 + d_t] = f2bs(q + brr);
        }
        *(uint4*)u8 = rv0i;
#pragma unroll
        for (int u = 0; u < 8; ++u) Rt[(wave * 8 + u) * 72 + d_t] = u8[u];
        *(uint4*)u8 = rv1i;
#pragma unroll
        for (int u = 0; u < 8; ++u) Rt[((4 + wave) * 8 + u) * 72 + d_t] = u8[u];
    }

    // ---- prefetch first tile's K/V/R into registers ----
    uint4 kv0, kv1, vv0, vv1, rv0, rv1;
    {
        const int j0 = j0_lo;
        const bf16* krow = whb + (size_t)(1024 + hw + d_t) * QLEN + j0;
        kv0 = *(const uint4*)(krow + wave * 8);
        kv1 = *(const uint4*)(krow + (4 + wave) * 8);
        vv0 = *(const uint4*)(whb + (size_t)(2048 + hw + dv0) * QLEN + j0 + jv0);
        vv1 = *(const uint4*)(whb + (size_t)(2048 + hw + dv1) * QLEN + j0 + jv0);
        const int pn = j0 - i0 + QLEN;
        const bf16* rrow = rhk + (size_t)(hw + d_t) * QLEN;
        int p0 = pn + wave * 8;
        if (p0 + 7 < QLEN) rv0 = *(const uint4*)(rrow + p0);
        else {
            unsigned short u8[8];
#pragma unroll
            for (int u = 0; u < 8; ++u)
                u8[u] = (p0 + u < QLEN) ? *(const unsigned short*)(rrow + p0 + u) : 0;
            rv0 = *(uint4*)u8;
        }
        int p1 = pn + (4 + wave) * 8;
        if (p1 + 7 < QLEN) rv1 = *(const uint4*)(rrow + p1);
        else {
            unsigned short u8[8];
#pragma unroll
            for (int u = 0; u < 8; ++u)
                u8[u] = (p1 + u < QLEN) ? *(const unsigned short*)(rrow + p1 + u) : 0;
            rv1 = *(uint4*)u8;
        }
    }
    __syncthreads(); // one-time full drain: Q/R staging visible

    const int qrow_off = (wave * 16 + l15) * 72 + quad * 8;
    bf16x8 qw0 = *(const bf16x8*)&Qrw[qrow_off];
    bf16x8 qw1 = *(const bf16x8*)&Qrw[qrow_off + 32];
    bf16x8 qr0 = *(const bf16x8*)&Qrr[qrow_off];
    bf16x8 qr1 = *(const bf16x8*)&Qrr[qrow_off + 32];

    // ---- pre-compute G lower half (cols [0,64) of first window) ----
    f32x4 g_acc[8];
#pragma unroll
    for (int nt = 0; nt < 4; ++nt) {
        f32x4 g = (f32x4){0.f, 0.f, 0.f, 0.f};
        int ro = (nt * 16 + l15) * 72 + quad * 8;
        bf16x8 b0 = *(const bf16x8*)&Rt[ro];
        bf16x8 b1 = *(const bf16x8*)&Rt[ro + 32];
        g = __builtin_amdgcn_mfma_f32_16x16x32_bf16(qr0, b0, g, 0, 0, 0);
        g = __builtin_amdgcn_mfma_f32_16x16x32_bf16(qr1, b1, g, 0, 0, 0);
        g_acc[nt] = g;
    }

    float l_r[4] = {0.f, 0.f, 0.f, 0.f};
    f32x4 o_acc[4];
#pragma unroll
    for (int dj = 0; dj < 4; ++dj) o_acc[dj] = (f32x4){0.f, 0.f, 0.f, 0.f};

    for (int jt = jt_lo; jt <= it; ++jt) {
        const int j0 = jt * 64;
        // (a) raw barrier: prior-phase LDS reads consumed by MFMA lgkm deps;
        // prefetch vmcnt rides through.
        asm volatile("" ::: "memory");
        __builtin_amdgcn_s_barrier();
        asm volatile("" ::: "memory");

        // ---- LDS writes from prefetched regs ----
        {
            unsigned short u8[8];
            *(uint4*)u8 = kv0;
#pragma unroll
            for (int u = 0; u < 8; ++u) Kt[(wave * 8 + u) * 72 + d_t] = u8[u];
            *(uint4*)u8 = kv1;
#pragma unroll
            for (int u = 0; u < 8; ++u) Kt[((4 + wave) * 8 + u) * 72 + d_t] = u8[u];
            *(uint4*)&Vs[dv0 * 72 + jv0] = vv0;
            *(uint4*)&Vs[dv1 * 72 + jv0] = vv1;
            *(uint4*)u8 = rv0;
#pragma unroll
            for (int u = 0; u < 8; ++u) Rt[(wave * 8 + u) * 72 + d_t] = u8[u];
            *(uint4*)u8 = rv1;
#pragma unroll
            for (int u = 0; u < 8; ++u) Rt[((4 + wave) * 8 + u) * 72 + d_t] = u8[u];
        }

        // ---- prefetch NEXT tile ----
        if (jt < it) {
            const int j0n = j0 + 64;
            const bf16* krow = whb + (size_t)(1024 + hw + d_t) * QLEN + j0n;
            kv0 = *(const uint4*)(krow + wave * 8);
            kv1 = *(const uint4*)(krow + (4 + wave) * 8);
            vv0 = *(const uint4*)(whb + (size_t)(2048 + hw + dv0) * QLEN + j0n + jv0);
            vv1 = *(const uint4*)(whb + (size_t)(2048 + hw + dv1) * QLEN + j0n + jv0);
            const int pn = j0n - i0 + QLEN; // may exceed QLEN near the diagonal
            const bf16* rrow = rhk + (size_t)(hw + d_t) * QLEN;
            int p0 = pn + wave * 8;
            if (p0 + 7 < QLEN) rv0 = *(const uint4*)(rrow + p0);
            else {
                unsigned short u8[8];
#pragma unroll
                for (int u = 0; u < 8; ++u)
                    u8[u] = (p0 + u < QLEN) ? *(const unsigned short*)(rrow + p0 + u) : 0;
                rv0 = *(uint4*)u8;
            }
            int p1 = pn + (4 + wave) * 8;
            if (p1 + 7 < QLEN) rv1 = *(const uint4*)(rrow + p1);
            else {
                unsigned short u8[8];
#pragma unroll
                for (int u = 0; u < 8; ++u)
                    u8[u] = (p1 + u < QLEN) ? *(const unsigned short*)(rrow + p1 + u) : 0;
                rv1 = *(uint4*)u8;
            }
        }
        // (b) ds_writes visible to all waves; vmcnt deliberately NOT drained.
        asm volatile("s_waitcnt lgkmcnt(0)" ::: "memory");
        __builtin_amdgcn_s_barrier();
        asm volatile("" ::: "memory");

        // ---- AC MFMAs (8) ----
        f32x4 s_acc[4];
#pragma unroll
        for (int nj = 0; nj < 4; ++nj) {
            s_acc[nj] = (f32x4){0.f, 0.f, 0.f, 0.f};
            int ko = (nj * 16 + l15) * 72 + quad * 8;
            bf16x8 b0 = *(const bf16x8*)&Kt[ko];
            bf16x8 b1 = *(const bf16x8*)&Kt[ko + 32];
            s_acc[nj] = __builtin_amdgcn_mfma_f32_16x16x32_bf16(qw0, b0, s_acc[nj], 0, 0, 0);
            s_acc[nj] = __builtin_amdgcn_mfma_f32_16x16x32_bf16(qw1, b1, s_acc[nj], 0, 0, 0);
        }
        // ---- G upper-half MFMAs (8): window cols 64 + nt*16 + l15 ----
#pragma unroll
        for (int nt = 0; nt < 4; ++nt) {
            f32x4 g = (f32x4){0.f, 0.f, 0.f, 0.f};
            int ro = (nt * 16 + l15) * 72 + quad * 8;
            bf16x8 b0 = *(const bf16x8*)&Rt[ro];
            bf16x8 b1 = *(const bf16x8*)&Rt[ro + 32];
            g = __builtin_amdgcn_mfma_f32_16x16x32_bf16(qr0, b0, g, 0, 0, 0);
            g = __builtin_amdgcn_mfma_f32_16x16x32_bf16(qr1, b1, g, 0, 0, 0);
            g_acc[4 + nt] = g;
        }

        // ---- BD redistribution (ds_bpermute, wave-local) + no-max softmax ----
        // G[i][t]: lane (q,sl) reg r of g_acc[nt] holds i=16w+4q+r, t=16nt+sl.
        // Dest (q',l15') (nj,r') needs t = 16nj+l15'-16w-4q'-r'+63:
        //   same q', same r'; src l15 = (l15'-4q'-r'-1)&15; reg n0=3-w+nj,
        //   +1 when l15' > 4q'+r' (wave/nj-independent). bd stays f32.
        float rs[4] = {0.f, 0.f, 0.f, 0.f};
#define SOFTMAX_W(W)                                                            \
        {                                                                       \
            _Pragma("unroll")                                                   \
            for (int nj = 0; nj < 4; ++nj) {                                    \
                _Pragma("unroll")                                               \
                for (int r = 0; r < 4; ++r) {                                   \
                    const int n0 = 3 - (W) + nj;                                \
                    int sa = ((lane & 48) | ((l15 - 4 * quad - r - 1) & 15)) << 2; \
                    float blo = __int_as_float(__builtin_amdgcn_ds_bpermute(    \
                        sa, __float_as_int(g_acc[n0][r])));                     \
                    float bhi = __int_as_float(__builtin_amdgcn_ds_bpermute(    \
                        sa, __float_as_int(g_acc[n0 + 1][r])));                 \
                    float bd = (l15 > 4 * quad + r) ? bhi : blo;                \
                    int i_loc = (W) * 16 + quad * 4 + r;                        \
                    int j_loc = nj * 16 + l15;                                  \
                    int diff = (i0 + i_loc) - (j0 + j_loc);                     \
                    float pv = 0.f;                                             \
                    if (diff >= 0 && diff < LOCAL_SIZE)                         \
                        pv = __expf((s_acc[nj][r] + bd) * 0.125f);              \
                    Ps[i_loc * 72 + j_loc] = f2bs(pv);                          \
                    rs[r] += pv;                                                \
                }                                                               \
            }                                                                   \
        }
        if      (wave == 0) SOFTMAX_W(0)
        else if (wave == 1) SOFTMAX_W(1)
        else if (wave == 2) SOFTMAX_W(2)
        else                SOFTMAX_W(3)
#undef SOFTMAX_W

#pragma unroll
        for (int r = 0; r < 4; ++r) {
            float v = rs[r];
            v += __shfl_xor(v, 1);
            v += __shfl_xor(v, 2);
            v += __shfl_xor(v, 4);
            v += __shfl_xor(v, 8);
            l_r[r] += v;
        }

        // ---- PV MFMAs (8); Ps is wave-local, Vs cross-wave (read-only) ----
        {
            int po = (wave * 16 + l15) * 72 + quad * 8;
            bf16x8 pa0 = *(const bf16x8*)&Ps[po];
            bf16x8 pa1 = *(const bf16x8*)&Ps[po + 32];
#pragma unroll
            for (int dj = 0; dj < 4; ++dj) {
                int vo = (dj * 16 + l15) * 72 + quad * 8;
                bf16x8 b0 = *(const bf16x8*)&Vs[vo];
                bf16x8 b1 = *(const bf16x8*)&Vs[vo + 32];
                o_acc[dj] = __builtin_amdgcn_mfma_f32_16x16x32_bf16(pa0, b0, o_acc[dj], 0, 0, 0);
                o_acc[dj] = __builtin_amdgcn_mfma_f32_16x16x32_bf16(pa1, b1, o_acc[dj], 0, 0, 0);
            }
        }

        // ---- shift G window: cols [64,128) become next iter's [0,64) ----
#pragma unroll
        for (int nt = 0; nt < 4; ++nt) g_acc[nt] = g_acc[nt + 4];
    }

    // ---- normalize and store (layout [b][q][h*64+d]) ----
#pragma unroll
    for (int r = 0; r < 4; ++r) {
        float inv = 1.f / l_r[r];
        int q = i0 + wave * 16 + quad * 4 + r;
        bf16* orow = av_out + ((size_t)b * QLEN + q) * D_MODEL + hw;
#pragma unroll
        for (int dj = 0; dj < 4; ++dj)
            orow[dj * 16 + l15] = __float2bfloat16(o_acc[dj][r] * inv);
    }
}

// ---------------------------------------------------------------------------
// Row LayerNorm in place (unchanged).
// ---------------------------------------------------------------------------
__global__ __launch_bounds__(256)
void ln_kernel(float* __restrict__ yt)
{
    const int b = blockIdx.y, q = blockIdx.x;
    float* row = yt + ((size_t)b * QLEN + q) * D_MODEL;
    const int t = threadIdx.x;
    float4 v = ((float4*)row)[t];
    float s  = v.x + v.y + v.z + v.w;
    float ss = v.x * v.x + v.y * v.y + v.z * v.z + v.w * v.w;
#pragma unroll
    for (int off = 32; off; off >>= 1) {
        s  += __shfl_down(s, off);
        ss += __shfl_down(ss, off);
    }
    __shared__ float sw[4], ssw[4];
    const int w = t >> 6;
    if ((t & 63) == 0) { sw[w] = s; ssw[w] = ss; }
    __syncthreads();
    float S  = sw[0] + sw[1] + sw[2] + sw[3];
    float SS = ssw[0] + ssw[1] + ssw[2] + ssw[3];
    float mu  = S / D_MODEL;
    float var = SS / D_MODEL - mu * mu;
    float rs  = rsqrtf(var + 1e-5f);
    v.x = (v.x - mu) * rs; v.y = (v.y - mu) * rs;
    v.z = (v.z - mu) * rs; v.w = (v.w - mu) * rs;
    ((float4*)row)[t] = v;
}

// ---------------------------------------------------------------------------
// Transpose y_t[b][q][o] fp32 -> out[b][o][q] (dtype per flag). Unchanged.
// ---------------------------------------------------------------------------
__global__ __launch_bounds__(256)
void transpose_out(const float* __restrict__ yt, void* __restrict__ out,
                   const int* __restrict__ flag)
{
    const int fl = *flag;
    const int b  = blockIdx.z;
    const int q0 = blockIdx.x * 32;
    const int o0 = blockIdx.y * 32;
    const int tx = threadIdx.x & 31, ty = threadIdx.x >> 5;
    __shared__ float T[32][33];
#pragma unroll
    for (int r = 0; r < 4; ++r) {
        int q = q0 + ty + r * 8;
        T[ty + r * 8][tx] = yt[((size_t)b * QLEN + q) * D_MODEL + o0 + tx];
    }
    __syncthreads();
#pragma unroll
    for (int r = 0; r < 4; ++r) {
        int o = o0 + ty + r * 8;
        size_t oi = ((size_t)b * D_MODEL + o) * QLEN + q0 + tx;
        float v = T[tx][ty + r * 8];
        if (fl) ((float*)out)[oi] = v;
        else    ((bf16*)out)[oi] = __float2bfloat16(v);
    }
}

// ---------------------------------------------------------------------------
extern "C" void kernel_launch(void* const* d_in, const int* in_sizes, int n_in,
                              void* d_out, int out_size, void* d_ws, size_t ws_size,
                              hipStream_t stream)
{
    const void* z1ss = d_in[0];
    const void* pos  = d_in[1];
    const void* u1ss = d_in[2];
    const void* Wqkv = d_in[3];
    const void* Wr   = d_in[4];
    const void* rwb  = d_in[5];
    const void* rrb  = d_in[6];
    const void* Wo   = d_in[7];
    const void* bo   = d_in[8];

    const size_t whE  = (size_t)BSZ * QKV3 * QLEN;     // 12,582,912 elems
    const size_t rhkE = (size_t)D_MODEL * QLEN;        //  2,097,152
    const size_t avE  = (size_t)BSZ * QLEN * D_MODEL;  //  4,194,304
    const size_t ztE  = avE;
    const size_t wqE  = (size_t)QKV3 * D_MODEL;        //  3,145,728
    const size_t wrE  = (size_t)D_MODEL * D_MODEL;     //  1,048,576
    const size_t woE  = wrE;

    char* ws = (char*)d_ws;
    bf16* wh   = (bf16*)ws;            // [B][3072][Q] o-major (q|k|v)
    bf16* rhk  = wh + whE;             // [1024][Q] o-major
    bf16* avec = rhk + rhkE;           // [B][Q][1024]
    bf16* post = avec;                 // overlay: dead before attn writes avec
    size_t baseB = (whE + rhkE + avE) * sizeof(bf16);
    bf16* zt  = (bf16*)(ws + baseB);
    bf16* wqb = zt + ztE;              // wqb|wrb|wob contiguous (convw_all)
    bf16* wrb = wqb + wqE;
    bf16* wob = wrb + wrE;
    float* yt = (float*)ws;            // overlays wh (dead after attn)

    const size_t t2B = baseB + ztE * sizeof(bf16) + 16;
    const size_t t1B = baseB + (ztE + wqE + wrE + woE) * sizeof(bf16) + 16;
    const int tier = (ws_size >= t1B) ? 1 : (ws_size >= t2B) ? 2 : 3;

    int* flag = (tier == 1) ? (int*)(wob + woE)
              : (tier == 2) ? (int*)(wqb)
                            : (int*)(ws + baseB);

    detect_kernel<<<1, 64, 0, stream>>>((const unsigned short*)Wqkv, flag);

    if (tier == 1) {
        // 0a. weights -> bf16 (one dispatch; outputs contiguous)
        convw_all<<<dim3((unsigned)((wqE + wrE + woE) / 2048)), 256, 0, stream>>>(
            Wqkv, Wr, Wo, wqb, flag);

        // 0b. transposes (one dispatch: z in [0,BSZ] with z==BSZ -> pos)
        tcvt_all<<<dim3(QLEN / 32, D_MODEL / 32, BSZ + 1), 256, 0, stream>>>(
            z1ss, pos, zt, post, flag);

        // 1+2. fused QKV + rhk GEMM
        gemm_qkvr<<<dim3(QLEN / 128, QKV3 / 128 + D_MODEL / 128, BSZ), 256, 0, stream>>>(
            wqb, wrb, zt, post, wh, rhk, u1ss, flag);

        // 3. MFMA banded flash attention v8 -> avec[b][q][1024]
        attn_mfma<<<dim3(QLEN / 64, N_HEAD, BSZ), 256, 0, stream>>>(
            wh, rhk, rwb, rrb, avec, flag);

        // 4. y_t[b][q][o] = avec . Wo^T + bo + zt
        gemm_glds<<<dim3(1024 / 128, 2048 / 128, BSZ), 256, 0, stream>>>(
            avec, (size_t)QLEN * D_MODEL,
            wob, 0,
            yt, 0, (size_t)QLEN * D_MODEL,
            zt, 0, (size_t)QLEN * D_MODEL,
            bo, 2,
            QLEN, D_MODEL, D_MODEL, flag);
    } else if (tier == 2) {
        // proven round-2 path
        tcvt_all<<<dim3(QLEN / 32, D_MODEL / 32, BSZ + 1), 256, 0, stream>>>(
            z1ss, pos, zt, post, flag);

        gemm_bf16<<<dim3(2048 / 128, 3072 / 128, BSZ), 256, 0, stream>>>(
            Wqkv, 2, 0,
            zt, 0, (size_t)QLEN * D_MODEL,
            wh, 1, (size_t)QKV3 * QLEN,
            u1ss, 2, (size_t)QKV3 * QLEN,
            nullptr, 0,
            QKV3, QLEN, D_MODEL, flag);

        gemm_bf16<<<dim3(2048 / 128, 1024 / 128, 1), 256, 0, stream>>>(
            Wr, 2, 0,
            post, 0, 0,
            rhk, 1, 0,
            nullptr, 0, 0,
            nullptr, 0,
            D_MODEL, QLEN, D_MODEL, flag);

        attn_mfma<<<dim3(QLEN / 64, N_HEAD, BSZ), 256, 0, stream>>>(
            wh, rhk, rwb, rrb, avec, flag);

        gemm_bf16<<<dim3(1024 / 128, 2048 / 128, BSZ), 256, 0, stream>>>(
            avec, 0, (size_t)QLEN * D_MODEL,
            Wo, 2, 0,
            yt, 0, (size_t)QLEN * D_MODEL,
            zt, 0, (size_t)QLEN * D_MODEL,
            bo, 2,
            QLEN, D_MODEL, D_MODEL, flag);
    } else {
        // fallback: proven gemm_tn path (in-GEMM transpose) + attn
        gemm_tn<<<dim3(2048 / 128, 3072 / 128, BSZ), 256, 0, stream>>>(
            Wqkv, 2, 0,
            z1ss, 2, 1, QLEN, (size_t)D_MODEL * QLEN,
            wh, 1, (size_t)QKV3 * QLEN,
            u1ss, 2, 0, (size_t)QKV3 * QLEN,
            nullptr, 0,
            QKV3, QLEN, D_MODEL, flag);
        gemm_tn<<<dim3(2048 / 128, 1024 / 128, 1), 256, 0, stream>>>(
            Wr, 2, 0,
            pos, 2, 1, QLEN, 0,
            rhk, 1, 0,
            nullptr, 0, 0, 0,
            nullptr, 0,
            D_MODEL, QLEN, D_MODEL, flag);
        attn_mfma<<<dim3(QLEN / 64, N_HEAD, BSZ), 256, 0, stream>>>(
            wh, rhk, rwb, rrb, avec, flag);
        gemm_tn<<<dim3(1024 / 128, 2048 / 128, BSZ), 256, 0, stream>>>(
            avec, 0, (size_t)QLEN * D_MODEL,
            Wo, 2, 0, D_MODEL, 0,
            yt, 0, (size_t)QLEN * D_MODEL,
            z1ss, 2, 1, (size_t)D_MODEL * QLEN,
            bo, 2,
            QLEN, D_MODEL, D_MODEL, flag);
    }

    // 5. LN in place on y_t rows
    ln_kernel<<<dim3(QLEN, BSZ), 256, 0, stream>>>(yt);

    // 6. transpose to out[b][o][q]
    transpose_out<<<dim3(QLEN / 32, D_MODEL / 32, BSZ), 256, 0, stream>>>(yt, d_out, flag);
}

// Round 8
// 382.574 us; speedup vs baseline: 1.0804x; 1.0611x over previous
//
#include <hip/hip_runtime.h>
#include <hip/hip_bf16.h>

#define D_MODEL 1024
#define N_HEAD 16
#define BSZ 2
#define QLEN 2048
#define LOCAL_SIZE 1000
#define QKV3 (3 * N_HEAD * 64) // 3072

typedef __hip_bfloat16 bf16;
typedef short bf16x8 __attribute__((ext_vector_type(8)));
typedef float f32x4 __attribute__((ext_vector_type(4)));

static __device__ __forceinline__ float b2f(bf16 x) { return __bfloat162float(x); }
static __device__ __forceinline__ float bits2f(unsigned short u) {
    return __uint_as_float(((unsigned int)u) << 16);
}
static __device__ __forceinline__ unsigned short f2bs(float x) {
    __hip_bfloat16 h = __float2bfloat16(x);
    return *(unsigned short*)&h;
}

// mode: 0 = always bf16, 1 = always fp32, 2 = follow runtime flag (raw harness tensor)
static __device__ __forceinline__ int rmode(int m, int fl) { return (m == 2) ? fl : m; }
static __device__ __forceinline__ float ldm(const void* p, size_t i, int isf) {
    return isf ? ((const float*)p)[i] : b2f(((const bf16*)p)[i]);
}
static __device__ __forceinline__ float4 ld4(const void* p, size_t i, int isf) {
    if (isf) return ((const float4*)p)[i >> 2];
    ushort4 u = ((const ushort4*)p)[i >> 2];
    float4 f;
    f.x = bits2f(u.x); f.y = bits2f(u.y); f.z = bits2f(u.z); f.w = bits2f(u.w);
    return f;
}
static __device__ __forceinline__ ushort4 cvt4(float4 f) {
    ushort4 u;
    u.x = f2bs(f.x); u.y = f2bs(f.y); u.z = f2bs(f.z); u.w = f2bs(f.w);
    return u;
}

// async global->LDS, 16 B per lane; LDS dest = wave-uniform base + lane*16
static __device__ __forceinline__ void glds16(const bf16* g, unsigned short* l) {
    __builtin_amdgcn_global_load_lds(
        (const __attribute__((address_space(1))) void*)g,
        (__attribute__((address_space(3))) void*)l,
        16, 0, 0);
}

// ---------------------------------------------------------------------------
// dtype detector (flag: 0 = bf16 data, 1 = fp32 data). Proven.
// ---------------------------------------------------------------------------
__global__ void detect_kernel(const unsigned short* __restrict__ w, int* __restrict__ flag)
{
    if (threadIdx.x == 0 && blockIdx.x == 0) {
        int good = 0;
        for (int i = 0; i < 256; ++i) {
            float v = bits2f(w[i]);
            if (v == v && fabsf(v) < 8.0f) ++good;
        }
        *flag = (good >= 240) ? 0 : 1;
    }
}

// ---------------------------------------------------------------------------
// Fused weight convert: Wqkv|Wr|Wo (raw) -> contiguous bf16 at wqb.
// ---------------------------------------------------------------------------
__global__ __launch_bounds__(256)
void convw_all(const void* __restrict__ wq, const void* __restrict__ wr,
               const void* __restrict__ wo, bf16* __restrict__ outp,
               const int* __restrict__ flag)
{
    const int fl = *flag;
    const int blk = blockIdx.x;
    const void* in; size_t segOff;
    if (blk < 1536)      { in = wq; segOff = (size_t)blk * 2048; }
    else if (blk < 2048) { in = wr; segOff = (size_t)(blk - 1536) * 2048; }
    else                 { in = wo; segOff = (size_t)(blk - 2048) * 2048; }
    const size_t ii = segOff + (size_t)threadIdx.x * 8;
    const size_t oi = (size_t)blk * 2048 + (size_t)threadIdx.x * 8;
    if (fl) {
        float4 a = ((const float4*)in)[ii / 4];
        float4 b = ((const float4*)in)[ii / 4 + 1];
        *(ushort4*)((unsigned short*)outp + oi)     = cvt4(a);
        *(ushort4*)((unsigned short*)outp + oi + 4) = cvt4(b);
    } else {
        *(uint4*)((unsigned short*)outp + oi) = ((const uint4*)in)[ii / 8];
    }
}

// ---------------------------------------------------------------------------
// Fused transpose+convert: z1ss (z<BSZ) and pos (z==BSZ) -> [q][d] bf16.
// ---------------------------------------------------------------------------
__global__ __launch_bounds__(256)
void tcvt_all(const void* __restrict__ z1ss, const void* __restrict__ pos,
              bf16* __restrict__ zt, bf16* __restrict__ post,
              const int* __restrict__ flag)
{
    const int fl = *flag;
    const int zb = blockIdx.z;
    const void* in = (zb < BSZ) ? z1ss : pos;
    const size_t inOff = (zb < BSZ) ? (size_t)zb * D_MODEL * QLEN : 0;
    bf16* outp = (zb < BSZ) ? zt + (size_t)zb * QLEN * D_MODEL : post;
    const int c0 = blockIdx.x * 32;   // col (q) in [0, QLEN)
    const int r0 = blockIdx.y * 32;   // row (d) in [0, D_MODEL)
    const int tx = threadIdx.x & 31, ty = threadIdx.x >> 5;
    __shared__ float T[32][33];
#pragma unroll
    for (int r = 0; r < 4; ++r) {
        int rr = r0 + ty + r * 8;
        T[ty + r * 8][tx] = ldm(in, inOff + (size_t)rr * QLEN + c0 + tx, fl);
    }
    __syncthreads();
#pragma unroll
    for (int r = 0; r < 4; ++r) {
        int cc = c0 + ty + r * 8;
        outp[(size_t)cc * D_MODEL + r0 + tx] = __float2bfloat16(T[tx][ty + r * 8]);
    }
}

// ---------------------------------------------------------------------------
// Fused QKV + rhk GEMM, glds-staged, v2: T4 counted-vmcnt + depth-2 prefetch.
//  Round-7 diagnosis: 2-phase loop with __syncthreads (= vmcnt(0) drain) gave
//  each tile's glds only ~400 cyc cover vs ~900-cyc HBM latency -> 255 TF,
//  MfmaUtil 9.6%. v2: 3 LDS buffers, loop =
//    { s_waitcnt vmcnt(4) (tile t done, t+1 stays in flight); s_barrier;
//      issue glds(t+2); ds_read(t); MFMA(t) }
//  Race-safety: glds(t+2) overwrites buf[(t-1)%3] only after barrier t, which
//  all waves reach after finishing tile t-1 reads; per-wave vmcnt before the
//  barrier makes tile t fully visible at barrier exit (m201/T4 pattern).
// ---------------------------------------------------------------------------
__global__ __launch_bounds__(256)
void gemm_qkvr(const bf16* __restrict__ wqb, const bf16* __restrict__ wrb,
               const bf16* __restrict__ zt, const bf16* __restrict__ post,
               bf16* __restrict__ wh, bf16* __restrict__ rhk,
               const void* __restrict__ u1ss, const int* __restrict__ flag)
{
    const int fl = *flag;
    const int bz = blockIdx.z;
    const int by = blockIdx.y;
    const bool isR = by >= (QKV3 / 128);
    if (isR && bz) return;
    const int n0 = blockIdx.x * 128;
    const int m0 = (isR ? by - QKV3 / 128 : by) * 128;
    const int K = D_MODEL, N = QLEN;

    const bf16* A = isR ? wrb : wqb;
    const bf16* B = isR ? post : zt + (size_t)bz * (size_t)QLEN * D_MODEL;
    bf16* C       = isR ? rhk  : wh + (size_t)bz * (size_t)QKV3 * QLEN;
    const size_t uOff = (size_t)bz * (size_t)QKV3 * QLEN;

    const int tid = threadIdx.x;
    const int wave = tid >> 6, lane = tid & 63;
    const int quad = lane >> 4, l15 = lane & 15;
    const int wm = (wave >> 1) * 64, wn = (wave & 1) * 64;

    __shared__ __align__(16) unsigned short A_s[3][128 * 32];
    __shared__ __align__(16) unsigned short B_s[3][128 * 32];

    const int srow = wave * 32 + (lane >> 2);
    const int scol = (lane & 3) * 8;
    const bf16* Ag = A + (size_t)(m0 + srow) * K + scol;
    const bf16* Bg = B + (size_t)(n0 + srow) * K + scol;
    const int sbase = wave * 1024;

    f32x4 acc[4][4];
#pragma unroll
    for (int i = 0; i < 4; ++i)
#pragma unroll
        for (int j = 0; j < 4; ++j) acc[i][j] = (f32x4){0.f, 0.f, 0.f, 0.f};

    // prologue: stage tiles 0 and 1 (K = 1024 here, always >= 64)
    glds16(Ag,                        &A_s[0][sbase]);
    glds16(Ag + (size_t)16 * K,       &A_s[0][sbase + 512]);
    glds16(Bg,                        &B_s[0][sbase]);
    glds16(Bg + (size_t)16 * K,       &B_s[0][sbase + 512]);
    glds16(Ag + 32,                   &A_s[1][sbase]);
    glds16(Ag + (size_t)16 * K + 32,  &A_s[1][sbase + 512]);
    glds16(Bg + 32,                   &B_s[1][sbase]);
    glds16(Bg + (size_t)16 * K + 32,  &B_s[1][sbase + 512]);

    int cur = 0;
    for (int k0 = 0; k0 < K; k0 += 32) {
        // drain ONLY tile t (oldest 4 glds); tile t+1 stays in flight
        if (k0 + 32 < K) asm volatile("s_waitcnt vmcnt(4) lgkmcnt(0)" ::: "memory");
        else             asm volatile("s_waitcnt vmcnt(0) lgkmcnt(0)" ::: "memory");
        __builtin_amdgcn_s_barrier();
        asm volatile("" ::: "memory");

        const int kn = k0 + 64;
        if (kn < K) {
            const int nb = (cur >= 1) ? cur - 1 : 2; // (cur+2)%3
            glds16(Ag + kn,                  &A_s[nb][sbase]);
            glds16(Ag + (size_t)16 * K + kn, &A_s[nb][sbase + 512]);
            glds16(Bg + kn,                  &B_s[nb][sbase]);
            glds16(Bg + (size_t)16 * K + kn, &B_s[nb][sbase + 512]);
        }
        bf16x8 a[4], bb[4];
#pragma unroll
        for (int i = 0; i < 4; ++i)
            a[i] = *(const bf16x8*)&A_s[cur][(wm + i * 16 + l15) * 32 + quad * 8];
#pragma unroll
        for (int j = 0; j < 4; ++j)
            bb[j] = *(const bf16x8*)&B_s[cur][(wn + j * 16 + l15) * 32 + quad * 8];
#pragma unroll
        for (int i = 0; i < 4; ++i)
#pragma unroll
            for (int j = 0; j < 4; ++j)
                acc[i][j] = __builtin_amdgcn_mfma_f32_16x16x32_bf16(a[i], bb[j], acc[i][j], 0, 0, 0);
        cur = (cur == 2) ? 0 : cur + 1;
    }

#pragma unroll
    for (int i = 0; i < 4; ++i) {
#pragma unroll
        for (int j = 0; j < 4; ++j) {
            int n = n0 + wn + j * 16 + l15;
#pragma unroll
            for (int r = 0; r < 4; ++r) {
                int m = m0 + wm + i * 16 + quad * 4 + r;
                float v = acc[i][j][r];
                if (!isR) v += ldm(u1ss, uOff + (size_t)m * N + n, fl);
                C[(size_t)m * N + n] = __float2bfloat16(v);
            }
        }
    }
}

// ---------------------------------------------------------------------------
// glds GEMM v2 (same T4 counted-vmcnt + depth-2 prefetch as gemm_qkvr).
// C[b][m][n] = A[b][m][k] * B[b][n][k] (+add)(+bias). A,B bf16. 128x128, BK=32.
// ---------------------------------------------------------------------------
__global__ __launch_bounds__(256)
void gemm_glds(const bf16* __restrict__ A, size_t sAb,
               const bf16* __restrict__ B, size_t sBb,
               void* __restrict__ C, int c_is_bf16, size_t sCb,
               const void* __restrict__ addm, int mAdd, size_t sAddb,
               const void* __restrict__ bias, int mBias,
               int M, int N, int K, const int* __restrict__ flag)
{
    const int fl = *flag;
    const int fAdd = rmode(mAdd, fl), fBias = rmode(mBias, fl);

    const int bz = blockIdx.z;
    const int n0 = blockIdx.x * 128;
    const int m0 = blockIdx.y * 128;
    const int tid = threadIdx.x;
    const int wave = tid >> 6, lane = tid & 63;
    const int quad = lane >> 4, l15 = lane & 15;
    const int wm = (wave >> 1) * 64, wn = (wave & 1) * 64;

    __shared__ __align__(16) unsigned short A_s[3][128 * 32];
    __shared__ __align__(16) unsigned short B_s[3][128 * 32];

    const int srow = wave * 32 + (lane >> 2);
    const int scol = (lane & 3) * 8;
    const bf16* Ag = A + (size_t)bz * sAb + (size_t)(m0 + srow) * K + scol;
    const bf16* Bg = B + (size_t)bz * sBb + (size_t)(n0 + srow) * K + scol;
    const int sbase = wave * 1024;

    f32x4 acc[4][4];
#pragma unroll
    for (int i = 0; i < 4; ++i)
#pragma unroll
        for (int j = 0; j < 4; ++j) acc[i][j] = (f32x4){0.f, 0.f, 0.f, 0.f};

    // prologue: stage tiles 0 and (if present) 1
    glds16(Ag,                        &A_s[0][sbase]);
    glds16(Ag + (size_t)16 * K,       &A_s[0][sbase + 512]);
    glds16(Bg,                        &B_s[0][sbase]);
    glds16(Bg + (size_t)16 * K,       &B_s[0][sbase + 512]);
    if (32 < K) {
        glds16(Ag + 32,                   &A_s[1][sbase]);
        glds16(Ag + (size_t)16 * K + 32,  &A_s[1][sbase + 512]);
        glds16(Bg + 32,                   &B_s[1][sbase]);
        glds16(Bg + (size_t)16 * K + 32,  &B_s[1][sbase + 512]);
    }

    int cur = 0;
    for (int k0 = 0; k0 < K; k0 += 32) {
        if (k0 + 32 < K) asm volatile("s_waitcnt vmcnt(4) lgkmcnt(0)" ::: "memory");
        else             asm volatile("s_waitcnt vmcnt(0) lgkmcnt(0)" ::: "memory");
        __builtin_amdgcn_s_barrier();
        asm volatile("" ::: "memory");

        const int kn = k0 + 64;
        if (kn < K) {
            const int nb = (cur >= 1) ? cur - 1 : 2; // (cur+2)%3
            glds16(Ag + kn,                  &A_s[nb][sbase]);
            glds16(Ag + (size_t)16 * K + kn, &A_s[nb][sbase + 512]);
            glds16(Bg + kn,                  &B_s[nb][sbase]);
            glds16(Bg + (size_t)16 * K + kn, &B_s[nb][sbase + 512]);
        }
        bf16x8 a[4], bb[4];
#pragma unroll
        for (int i = 0; i < 4; ++i)
            a[i] = *(const bf16x8*)&A_s[cur][(wm + i * 16 + l15) * 32 + quad * 8];
#pragma unroll
        for (int j = 0; j < 4; ++j)
            bb[j] = *(const bf16x8*)&B_s[cur][(wn + j * 16 + l15) * 32 + quad * 8];
#pragma unroll
        for (int i = 0; i < 4; ++i)
#pragma unroll
            for (int j = 0; j < 4; ++j)
                acc[i][j] = __builtin_amdgcn_mfma_f32_16x16x32_bf16(a[i], bb[j], acc[i][j], 0, 0, 0);
        cur = (cur == 2) ? 0 : cur + 1;
    }

    const size_t cb = (size_t)bz * sCb;
#pragma unroll
    for (int i = 0; i < 4; ++i) {
#pragma unroll
        for (int j = 0; j < 4; ++j) {
            int n = n0 + wn + j * 16 + l15;
#pragma unroll
            for (int r = 0; r < 4; ++r) {
                int m = m0 + wm + i * 16 + quad * 4 + r;
                float v = acc[i][j][r];
                if (addm) v += ldm(addm, (size_t)bz * sAddb + (size_t)m * N + n, fAdd);
                if (bias) v += ldm(bias, (size_t)n, fBias);
                size_t ci = cb + (size_t)m * N + n;
                if (c_is_bf16) ((bf16*)C)[ci] = __float2bfloat16(v);
                else           ((float*)C)[ci] = v;
            }
        }
    }
}

// ---------------------------------------------------------------------------
// Software-pipelined MFMA TN-GEMM (tier-2 fallback, proven).
// ---------------------------------------------------------------------------
__global__ __launch_bounds__(256)
void gemm_bf16(const void* __restrict__ A, int mA, size_t sAb,
               const void* __restrict__ B, int mB, size_t sBb,
               void* __restrict__ C, int c_is_bf16, size_t sCb,
               const void* __restrict__ addm, int mAdd, size_t sAddb,
               const void* __restrict__ bias, int mBias,
               int M, int N, int K, const int* __restrict__ flag)
{
    const int fl = *flag;
    const int fA = rmode(mA, fl), fB = rmode(mB, fl);
    const int fAdd = rmode(mAdd, fl), fBias = rmode(mBias, fl);

    const int bz = blockIdx.z;
    const int n0 = blockIdx.x * 128;
    const int m0 = blockIdx.y * 128;
    const int tid = threadIdx.x;
    const int wave = tid >> 6, lane = tid & 63;
    const int quad = lane >> 4, l15 = lane & 15;
    const int wm = (wave >> 1) * 64, wn = (wave & 1) * 64;

    __shared__ unsigned short A_s[128][40];
    __shared__ unsigned short B_s[128][40];

    const int r0c = tid >> 2,         c0c = tid & 3;
    const int r1c = (tid + 256) >> 2, c1c = tid & 3;

    const size_t aOff = (size_t)bz * sAb;
    const size_t bOff = (size_t)bz * sBb;
    const bf16*  Ah = (const bf16*)A;
    const float* Af = (const float*)A;
    const bf16*  Bh = (const bf16*)B;
    const float* Bf = (const float*)B;

    uint4 pa[4], pb[4];

#define LOAD_OP(p, fX, Xh, Xf, xOff, R0, C0, R1, C1, base, k0)                          \
    do {                                                                                \
        if (!fX) {                                                                      \
            p[0] = *(const uint4*)(Xh + xOff + (size_t)(base + R0) * K + (k0) + C0 * 8);\
            p[1] = *(const uint4*)(Xh + xOff + (size_t)(base + R1) * K + (k0) + C1 * 8);\
        } else {                                                                        \
            const float* q0 = Xf + xOff + (size_t)(base + R0) * K + (k0) + C0 * 8;      \
            const float* q1 = Xf + xOff + (size_t)(base + R1) * K + (k0) + C1 * 8;      \
            p[0] = *(const uint4*)q0; p[1] = *(const uint4*)(q0 + 4);                   \
            p[2] = *(const uint4*)q1; p[3] = *(const uint4*)(q1 + 4);                   \
        }                                                                               \
    } while (0)

#define WRITE_OP(p, fX, S, R0, C0, R1, C1)                                              \
    do {                                                                                \
        if (!fX) {                                                                      \
            *(uint4*)&S[R0][C0 * 8] = p[0];                                             \
            *(uint4*)&S[R1][C1 * 8] = p[1];                                             \
        } else {                                                                        \
            float4 f0 = *(float4*)&p[0], f1 = *(float4*)&p[1];                          \
            float4 f2 = *(float4*)&p[2], f3 = *(float4*)&p[3];                          \
            *(ushort4*)&S[R0][C0 * 8]     = cvt4(f0);                                   \
            *(ushort4*)&S[R0][C0 * 8 + 4] = cvt4(f1);                                   \
            *(ushort4*)&S[R1][C1 * 8]     = cvt4(f2);                                   \
            *(ushort4*)&S[R1][C1 * 8 + 4] = cvt4(f3);                                   \
        }                                                                               \
    } while (0)

    f32x4 acc[4][4];
#pragma unroll
    for (int i = 0; i < 4; ++i)
#pragma unroll
        for (int j = 0; j < 4; ++j) acc[i][j] = (f32x4){0.f, 0.f, 0.f, 0.f};

    LOAD_OP(pa, fA, Ah, Af, aOff, r0c, c0c, r1c, c1c, m0, 0);
    LOAD_OP(pb, fB, Bh, Bf, bOff, r0c, c0c, r1c, c1c, n0, 0);

    for (int k0 = 0; k0 < K; k0 += 32) {
        WRITE_OP(pa, fA, A_s, r0c, c0c, r1c, c1c);
        WRITE_OP(pb, fB, B_s, r0c, c0c, r1c, c1c);
        __syncthreads();

        const int kn = k0 + 32;
        if (kn < K) {
            LOAD_OP(pa, fA, Ah, Af, aOff, r0c, c0c, r1c, c1c, m0, kn);
            LOAD_OP(pb, fB, Bh, Bf, bOff, r0c, c0c, r1c, c1c, n0, kn);
        }

        bf16x8 a[4], bb[4];
#pragma unroll
        for (int i = 0; i < 4; ++i)
            a[i] = *(const bf16x8*)&A_s[wm + i * 16 + l15][quad * 8];
#pragma unroll
        for (int j = 0; j < 4; ++j)
            bb[j] = *(const bf16x8*)&B_s[wn + j * 16 + l15][quad * 8];
#pragma unroll
        for (int i = 0; i < 4; ++i)
#pragma unroll
            for (int j = 0; j < 4; ++j)
                acc[i][j] = __builtin_amdgcn_mfma_f32_16x16x32_bf16(a[i], bb[j], acc[i][j], 0, 0, 0);
        __syncthreads();
    }
#undef LOAD_OP
#undef WRITE_OP

    const size_t cb = (size_t)bz * sCb;
#pragma unroll
    for (int i = 0; i < 4; ++i) {
#pragma unroll
        for (int j = 0; j < 4; ++j) {
            int n = n0 + wn + j * 16 + l15;
#pragma unroll
            for (int r = 0; r < 4; ++r) {
                int m = m0 + wm + i * 16 + quad * 4 + r;
                float v = acc[i][j][r];
                if (addm) v += ldm(addm, (size_t)bz * sAddb + (size_t)m * N + n, fAdd);
                if (bias) v += ldm(bias, (size_t)n, fBias);
                size_t ci = cb + (size_t)m * N + n;
                if (c_is_bf16) ((bf16*)C)[ci] = __float2bfloat16(v);
                else           ((float*)C)[ci] = v;
            }
        }
    }
}

// ---------------------------------------------------------------------------
// Old MFMA TN-GEMM (small-workspace fallback only).
// ---------------------------------------------------------------------------
__global__ __launch_bounds__(256)
void gemm_tn(const void* __restrict__ A, int mA, size_t sAb,
             const void* __restrict__ Bsrc, int mB, int bTrans, int ldB, size_t sBb,
             void* __restrict__ C, int c_is_bf16, size_t sCb,
             const void* __restrict__ addm, int mAdd, int addT, size_t sAddb,
             const void* __restrict__ bias, int mBias,
             int M, int N, int K, const int* __restrict__ flag)
{
    const int fl = *flag;
    const int fA = rmode(mA, fl), fB = rmode(mB, fl);
    const int fAdd = rmode(mAdd, fl), fBias = rmode(mBias, fl);

    const int bz = blockIdx.z;
    const int n0 = blockIdx.x * 128;
    const int m0 = blockIdx.y * 128;
    const int tid = threadIdx.x;
    const int wave = tid >> 6, lane = tid & 63;
    const int quad = lane >> 4, l15 = lane & 15;
    const int wm = (wave >> 1) * 64, wn = (wave & 1) * 64;

    __shared__ unsigned short A_s[128][40];
    __shared__ unsigned short B_s[128][40];

    const size_t aBase = (size_t)bz * sAb;
    const size_t bBase = (size_t)bz * sBb;

    f32x4 acc[4][4];
#pragma unroll
    for (int i = 0; i < 4; ++i)
#pragma unroll
        for (int j = 0; j < 4; ++j) acc[i][j] = (f32x4){0.f, 0.f, 0.f, 0.f};

    for (int k0 = 0; k0 < K; k0 += 32) {
#pragma unroll
        for (int g = 0; g < 4; ++g) {
            int c = tid + g * 256;
            int m = c >> 3, kc = (c & 7) * 4;
            float4 f = ld4(A, aBase + (size_t)(m0 + m) * K + k0 + kc, fA);
            *(ushort4*)&A_s[m][kc] = cvt4(f);
        }
        if (!bTrans) {
#pragma unroll
            for (int g = 0; g < 4; ++g) {
                int c = tid + g * 256;
                int n = c >> 3, kc = (c & 7) * 4;
                float4 f = ld4(Bsrc, bBase + (size_t)(n0 + n) * ldB + k0 + kc, fB);
                *(ushort4*)&B_s[n][kc] = cvt4(f);
            }
        } else {
#pragma unroll
            for (int g = 0; g < 4; ++g) {
                int c = tid + g * 256;
                int k = c >> 5, nc = (c & 31) * 4;
                float4 f = ld4(Bsrc, bBase + (size_t)(k0 + k) * ldB + n0 + nc, fB);
                ushort4 u = cvt4(f);
                B_s[nc + 0][k] = u.x;
                B_s[nc + 1][k] = u.y;
                B_s[nc + 2][k] = u.z;
                B_s[nc + 3][k] = u.w;
            }
        }
        __syncthreads();

        bf16x8 a[4], bb[4];
#pragma unroll
        for (int i = 0; i < 4; ++i)
            a[i] = *(const bf16x8*)&A_s[wm + i * 16 + l15][quad * 8];
#pragma unroll
        for (int j = 0; j < 4; ++j)
            bb[j] = *(const bf16x8*)&B_s[wn + j * 16 + l15][quad * 8];
#pragma unroll
        for (int i = 0; i < 4; ++i)
#pragma unroll
            for (int j = 0; j < 4; ++j)
                acc[i][j] = __builtin_amdgcn_mfma_f32_16x16x32_bf16(a[i], bb[j], acc[i][j], 0, 0, 0);
        __syncthreads();
    }

    const size_t cb = (size_t)bz * sCb;
#pragma unroll
    for (int i = 0; i < 4; ++i) {
#pragma unroll
        for (int j = 0; j < 4; ++j) {
            int n = n0 + wn + j * 16 + l15;
#pragma unroll
            for (int r = 0; r < 4; ++r) {
                int m = m0 + wm + i * 16 + quad * 4 + r;
                float v = acc[i][j][r];
                if (addm) {
                    size_t ai = (size_t)bz * sAddb +
                                (addT ? ((size_t)n * M + m) : ((size_t)m * N + n));
                    v += ldm(addm, ai, fAdd);
                }
                if (bias) v += ldm(bias, (size_t)n, fBias);
                size_t ci = cb + (size_t)m * N + n;
                if (c_is_bf16) ((bf16*)C)[ci] = __float2bfloat16(v);
                else           ((float*)C)[ci] = v;
            }
        }
    }
}

// ---------------------------------------------------------------------------
// MFMA banded flash attention v8 (round-7 proven: attn dropped out of top-5).
// ds_bpermute rel-shift, 2 barriers/iter, work-balance permutation.
// ---------------------------------------------------------------------------
__global__ __launch_bounds__(256)
void attn_mfma(const bf16* __restrict__ wh,  // [B][3072][Q]
               const bf16* __restrict__ rhk, // [1024][Q]
               const void* __restrict__ rwb, // [1024] raw
               const void* __restrict__ rrb, // [1024] raw
               bf16* __restrict__ av_out,    // [B][Q][1024]
               const int* __restrict__ flag)
{
    const int fl = *flag;
    // ---- work-balance decode: slot s gets it in {16+p, 24+p, p, 15-p} ----
    const int lidx = blockIdx.x + 32 * (blockIdx.y + (blockIdx.z << 4)); // [0,1024)
    const int slot = lidx >> 8;
    const int grp  = lidx & 255;
    const int hb   = grp & 31;
    const int prm  = grp >> 5; // [0,8)
    const int it   = (slot == 0) ? 16 + prm : (slot == 1) ? 24 + prm
                   : (slot == 2) ? prm : 15 - prm;
    const int h = hb & 15, b = hb >> 4;

    const int i0 = it * 64;
    const int tid = threadIdx.x;
    const int wave = tid >> 6, lane = tid & 63;
    const int quad = lane >> 4, l15 = lane & 15;
    const int hw = h * 64;

    __shared__ __align__(16) unsigned short sm[18432]; // 36,864 B
    unsigned short* Kt  = sm;           // [64][72]  K^T tile [j][d]
    unsigned short* Vs  = sm + 4608;    // [64][72]  V tile [d][j]
    unsigned short* Rt  = sm + 9216;    // [64][72]  new R half [t][d]
    unsigned short* Ps  = sm + 13824;   // [64][72]  P (own buffer, wave-local)
    unsigned short* Qrw = sm;           // init-only overlay
    unsigned short* Qrr = sm + 4608;    // init-only overlay

    const bf16* whb = wh + (size_t)b * QKV3 * QLEN;
    const int d_t = tid & 63;
    const int dv0 = tid >> 3, jv0 = (tid & 7) * 8;
    const int dv1 = (tid + 256) >> 3;

    int lo = i0 - (LOCAL_SIZE - 1);
    if (lo < 0) lo = 0;
    const int jt_lo = lo >> 6;
    const int j0_lo = jt_lo * 64;

    // ---- stage Q (+biases) and initial R lower half; all loads first ----
    {
        float brw = ldm(rwb, hw + d_t, fl);
        float brr = ldm(rrb, hw + d_t, fl);
        const bf16* qrow = whb + (size_t)(hw + d_t) * QLEN + i0;
        uint4 qv0 = *(const uint4*)(qrow + wave * 8);
        uint4 qv1 = *(const uint4*)(qrow + (4 + wave) * 8);
        // initial window cols t in [0,64): p = pbase0 + t; provably in [922,2047]
        const int pbase0 = j0_lo - i0 + QLEN - 64;
        const bf16* rrow = rhk + (size_t)(hw + d_t) * QLEN;
        uint4 rv0i = *(const uint4*)(rrow + pbase0 + wave * 8);
        uint4 rv1i = *(const uint4*)(rrow + pbase0 + (4 + wave) * 8);

        unsigned short u8[8];
        *(uint4*)u8 = qv0;
#pragma unroll
        for (int u = 0; u < 8; ++u) {
            float q = bits2f(u8[u]);
            Qrw[(wave * 8 + u) * 72 + d_t] = f2bs(q + brw);
            Qrr[(wave * 8 + u) * 72 + d_t] = f2bs(q + brr);
        }
        *(uint4*)u8 = qv1;
#pragma unroll
        for (int u = 0; u < 8; ++u) {
            float q = bits2f(u8[u]);
            Qrw[((4 + wave) * 8 + u) * 72 + d_t] = f2bs(q + brw);
            Qrr[((4 + wave) * 8 + u) * 72 + d_t] = f2bs(q + brr);
        }
        *(uint4*)u8 = rv0i;
#pragma unroll
        for (int u = 0; u < 8; ++u) Rt[(wave * 8 + u) * 72 + d_t] = u8[u];
        *(uint4*)u8 = rv1i;
#pragma unroll
        for (int u = 0; u < 8; ++u) Rt[((4 + wave) * 8 + u) * 72 + d_t] = u8[u];
    }

    // ---- prefetch first tile's K/V/R into registers ----
    uint4 kv0, kv1, vv0, vv1, rv0, rv1;
    {
        const int j0 = j0_lo;
        const bf16* krow = whb + (size_t)(1024 + hw + d_t) * QLEN + j0;
        kv0 = *(const uint4*)(krow + wave * 8);
        kv1 = *(const uint4*)(krow + (4 + wave) * 8);
        vv0 = *(const uint4*)(whb + (size_t)(2048 + hw + dv0) * QLEN + j0 + jv0);
        vv1 = *(const uint4*)(whb + (size_t)(2048 + hw + dv1) * QLEN + j0 + jv0);
        const int pn = j0 - i0 + QLEN;
        const bf16* rrow = rhk + (size_t)(hw + d_t) * QLEN;
        int p0 = pn + wave * 8;
        if (p0 + 7 < QLEN) rv0 = *(const uint4*)(rrow + p0);
        else {
            unsigned short u8[8];
#pragma unroll
            for (int u = 0; u < 8; ++u)
                u8[u] = (p0 + u < QLEN) ? *(const unsigned short*)(rrow + p0 + u) : 0;
            rv0 = *(uint4*)u8;
        }
        int p1 = pn + (4 + wave) * 8;
        if (p1 + 7 < QLEN) rv1 = *(const uint4*)(rrow + p1);
        else {
            unsigned short u8[8];
#pragma unroll
            for (int u = 0; u < 8; ++u)
                u8[u] = (p1 + u < QLEN) ? *(const unsigned short*)(rrow + p1 + u) : 0;
            rv1 = *(uint4*)u8;
        }
    }
    __syncthreads(); // one-time full drain: Q/R staging visible

    const int qrow_off = (wave * 16 + l15) * 72 + quad * 8;
    bf16x8 qw0 = *(const bf16x8*)&Qrw[qrow_off];
    bf16x8 qw1 = *(const bf16x8*)&Qrw[qrow_off + 32];
    bf16x8 qr0 = *(const bf16x8*)&Qrr[qrow_off];
    bf16x8 qr1 = *(const bf16x8*)&Qrr[qrow_off + 32];

    // ---- pre-compute G lower half (cols [0,64) of first window) ----
    f32x4 g_acc[8];
#pragma unroll
    for (int nt = 0; nt < 4; ++nt) {
        f32x4 g = (f32x4){0.f, 0.f, 0.f, 0.f};
        int ro = (nt * 16 + l15) * 72 + quad * 8;
        bf16x8 b0 = *(const bf16x8*)&Rt[ro];
        bf16x8 b1 = *(const bf16x8*)&Rt[ro + 32];
        g = __builtin_amdgcn_mfma_f32_16x16x32_bf16(qr0, b0, g, 0, 0, 0);
        g = __builtin_amdgcn_mfma_f32_16x16x32_bf16(qr1, b1, g, 0, 0, 0);
        g_acc[nt] = g;
    }

    float l_r[4] = {0.f, 0.f, 0.f, 0.f};
    f32x4 o_acc[4];
#pragma unroll
    for (int dj = 0; dj < 4; ++dj) o_acc[dj] = (f32x4){0.f, 0.f, 0.f, 0.f};

    for (int jt = jt_lo; jt <= it; ++jt) {
        const int j0 = jt * 64;
        // (a) raw barrier: prior-phase LDS reads consumed by MFMA lgkm deps;
        // prefetch vmcnt rides through.
        asm volatile("" ::: "memory");
        __builtin_amdgcn_s_barrier();
        asm volatile("" ::: "memory");

        // ---- LDS writes from prefetched regs ----
        {
            unsigned short u8[8];
            *(uint4*)u8 = kv0;
#pragma unroll
            for (int u = 0; u < 8; ++u) Kt[(wave * 8 + u) * 72 + d_t] = u8[u];
            *(uint4*)u8 = kv1;
#pragma unroll
            for (int u = 0; u < 8; ++u) Kt[((4 + wave) * 8 + u) * 72 + d_t] = u8[u];
            *(uint4*)&Vs[dv0 * 72 + jv0] = vv0;
            *(uint4*)&Vs[dv1 * 72 + jv0] = vv1;
            *(uint4*)u8 = rv0;
#pragma unroll
            for (int u = 0; u < 8; ++u) Rt[(wave * 8 + u) * 72 + d_t] = u8[u];
            *(uint4*)u8 = rv1;
#pragma unroll
            for (int u = 0; u < 8; ++u) Rt[((4 + wave) * 8 + u) * 72 + d_t] = u8[u];
        }

        // ---- prefetch NEXT tile ----
        if (jt < it) {
            const int j0n = j0 + 64;
            const bf16* krow = whb + (size_t)(1024 + hw + d_t) * QLEN + j0n;
            kv0 = *(const uint4*)(krow + wave * 8);
            kv1 = *(const uint4*)(krow + (4 + wave) * 8);
            vv0 = *(const uint4*)(whb + (size_t)(2048 + hw + dv0) * QLEN + j0n + jv0);
            vv1 = *(const uint4*)(whb + (size_t)(2048 + hw + dv1) * QLEN + j0n + jv0);
            const int pn = j0n - i0 + QLEN; // may exceed QLEN near the diagonal
            const bf16* rrow = rhk + (size_t)(hw + d_t) * QLEN;
            int p0 = pn + wave * 8;
            if (p0 + 7 < QLEN) rv0 = *(const uint4*)(rrow + p0);
            else {
                unsigned short u8[8];
#pragma unroll
                for (int u = 0; u < 8; ++u)
                    u8[u] = (p0 + u < QLEN) ? *(const unsigned short*)(rrow + p0 + u) : 0;
                rv0 = *(uint4*)u8;
            }
            int p1 = pn + (4 + wave) * 8;
            if (p1 + 7 < QLEN) rv1 = *(const uint4*)(rrow + p1);
            else {
                unsigned short u8[8];
#pragma unroll
                for (int u = 0; u < 8; ++u)
                    u8[u] = (p1 + u < QLEN) ? *(const unsigned short*)(rrow + p1 + u) : 0;
                rv1 = *(uint4*)u8;
            }
        }
        // (b) ds_writes visible to all waves; vmcnt deliberately NOT drained.
        asm volatile("s_waitcnt lgkmcnt(0)" ::: "memory");
        __builtin_amdgcn_s_barrier();
        asm volatile("" ::: "memory");

        // ---- AC MFMAs (8) ----
        f32x4 s_acc[4];
#pragma unroll
        for (int nj = 0; nj < 4; ++nj) {
            s_acc[nj] = (f32x4){0.f, 0.f, 0.f, 0.f};
            int ko = (nj * 16 + l15) * 72 + quad * 8;
            bf16x8 b0 = *(const bf16x8*)&Kt[ko];
            bf16x8 b1 = *(const bf16x8*)&Kt[ko + 32];
            s_acc[nj] = __builtin_amdgcn_mfma_f32_16x16x32_bf16(qw0, b0, s_acc[nj], 0, 0, 0);
            s_acc[nj] = __builtin_amdgcn_mfma_f32_16x16x32_bf16(qw1, b1, s_acc[nj], 0, 0, 0);
        }
        // ---- G upper-half MFMAs (8): window cols 64 + nt*16 + l15 ----
#pragma unroll
        for (int nt = 0; nt < 4; ++nt) {
            f32x4 g = (f32x4){0.f, 0.f, 0.f, 0.f};
            int ro = (nt * 16 + l15) * 72 + quad * 8;
            bf16x8 b0 = *(const bf16x8*)&Rt[ro];
            bf16x8 b1 = *(const bf16x8*)&Rt[ro + 32];
            g = __builtin_amdgcn_mfma_f32_16x16x32_bf16(qr0, b0, g, 0, 0, 0);
            g = __builtin_amdgcn_mfma_f32_16x16x32_bf16(qr1, b1, g, 0, 0, 0);
            g_acc[4 + nt] = g;
        }

        // ---- BD redistribution (ds_bpermute, wave-local) + no-max softmax ----
        float rs[4] = {0.f, 0.f, 0.f, 0.f};
#define SOFTMAX_W(W)                                                            \
        {                                                                       \
            _Pragma("unroll")                                                   \
            for (int nj = 0; nj < 4; ++nj) {                                    \
                _Pragma("unroll")                                               \
                for (int r = 0; r < 4; ++r) {                                   \
                    const int n0 = 3 - (W) + nj;                                \
                    int sa = ((lane & 48) | ((l15 - 4 * quad - r - 1) & 15)) << 2; \
                    float blo = __int_as_float(__builtin_amdgcn_ds_bpermute(    \
                        sa, __float_as_int(g_acc[n0][r])));                     \
                    float bhi = __int_as_float(__builtin_amdgcn_ds_bpermute(    \
                        sa, __float_as_int(g_acc[n0 + 1][r])));                 \
                    float bd = (l15 > 4 * quad + r) ? bhi : blo;                \
                    int i_loc = (W) * 16 + quad * 4 + r;                        \
                    int j_loc = nj * 16 + l15;                                  \
                    int diff = (i0 + i_loc) - (j0 + j_loc);                     \
                    float pv = 0.f;                                             \
                    if (diff >= 0 && diff < LOCAL_SIZE)                         \
                        pv = __expf((s_acc[nj][r] + bd) * 0.125f);              \
                    Ps[i_loc * 72 + j_loc] = f2bs(pv);                          \
                    rs[r] += pv;                                                \
                }                                                               \
            }                                                                   \
        }
        if      (wave == 0) SOFTMAX_W(0)
        else if (wave == 1) SOFTMAX_W(1)
        else if (wave == 2) SOFTMAX_W(2)
        else                SOFTMAX_W(3)
#undef SOFTMAX_W

#pragma unroll
        for (int r = 0; r < 4; ++r) {
            float v = rs[r];
            v += __shfl_xor(v, 1);
            v += __shfl_xor(v, 2);
            v += __shfl_xor(v, 4);
            v += __shfl_xor(v, 8);
            l_r[r] += v;
        }

        // ---- PV MFMAs (8); Ps is wave-local, Vs cross-wave (read-only) ----
        {
            int po = (wave * 16 + l15) * 72 + quad * 8;
            bf16x8 pa0 = *(const bf16x8*)&Ps[po];
            bf16x8 pa1 = *(const bf16x8*)&Ps[po + 32];
#pragma unroll
            for (int dj = 0; dj < 4; ++dj) {
                int vo = (dj * 16 + l15) * 72 + quad * 8;
                bf16x8 b0 = *(const bf16x8*)&Vs[vo];
                bf16x8 b1 = *(const bf16x8*)&Vs[vo + 32];
                o_acc[dj] = __builtin_amdgcn_mfma_f32_16x16x32_bf16(pa0, b0, o_acc[dj], 0, 0, 0);
                o_acc[dj] = __builtin_amdgcn_mfma_f32_16x16x32_bf16(pa1, b1, o_acc[dj], 0, 0, 0);
            }
        }

        // ---- shift G window: cols [64,128) become next iter's [0,64) ----
#pragma unroll
        for (int nt = 0; nt < 4; ++nt) g_acc[nt] = g_acc[nt + 4];
    }

    // ---- normalize and store (layout [b][q][h*64+d]) ----
#pragma unroll
    for (int r = 0; r < 4; ++r) {
        float inv = 1.f / l_r[r];
        int q = i0 + wave * 16 + quad * 4 + r;
        bf16* orow = av_out + ((size_t)b * QLEN + q) * D_MODEL + hw;
#pragma unroll
        for (int dj = 0; dj < 4; ++dj)
            orow[dj * 16 + l15] = __float2bfloat16(o_acc[dj][r] * inv);
    }
}

// ---------------------------------------------------------------------------
// Row LayerNorm in place (unchanged).
// ---------------------------------------------------------------------------
__global__ __launch_bounds__(256)
void ln_kernel(float* __restrict__ yt)
{
    const int b = blockIdx.y, q = blockIdx.x;
    float* row = yt + ((size_t)b * QLEN + q) * D_MODEL;
    const int t = threadIdx.x;
    float4 v = ((float4*)row)[t];
    float s  = v.x + v.y + v.z + v.w;
    float ss = v.x * v.x + v.y * v.y + v.z * v.z + v.w * v.w;
#pragma unroll
    for (int off = 32; off; off >>= 1) {
        s  += __shfl_down(s, off);
        ss += __shfl_down(ss, off);
    }
    __shared__ float sw[4], ssw[4];
    const int w = t >> 6;
    if ((t & 63) == 0) { sw[w] = s; ssw[w] = ss; }
    __syncthreads();
    float S  = sw[0] + sw[1] + sw[2] + sw[3];
    float SS = ssw[0] + ssw[1] + ssw[2] + ssw[3];
    float mu  = S / D_MODEL;
    float var = SS / D_MODEL - mu * mu;
    float rs  = rsqrtf(var + 1e-5f);
    v.x = (v.x - mu) * rs; v.y = (v.y - mu) * rs;
    v.z = (v.z - mu) * rs; v.w = (v.w - mu) * rs;
    ((float4*)row)[t] = v;
}

// ---------------------------------------------------------------------------
// Transpose y_t[b][q][o] fp32 -> out[b][o][q] (dtype per flag). Unchanged.
// ---------------------------------------------------------------------------
__global__ __launch_bounds__(256)
void transpose_out(const float* __restrict__ yt, void* __restrict__ out,
                   const int* __restrict__ flag)
{
    const int fl = *flag;
    const int b  = blockIdx.z;
    const int q0 = blockIdx.x * 32;
    const int o0 = blockIdx.y * 32;
    const int tx = threadIdx.x & 31, ty = threadIdx.x >> 5;
    __shared__ float T[32][33];
#pragma unroll
    for (int r = 0; r < 4; ++r) {
        int q = q0 + ty + r * 8;
        T[ty + r * 8][tx] = yt[((size_t)b * QLEN + q) * D_MODEL + o0 + tx];
    }
    __syncthreads();
#pragma unroll
    for (int r = 0; r < 4; ++r) {
        int o = o0 + ty + r * 8;
        size_t oi = ((size_t)b * D_MODEL + o) * QLEN + q0 + tx;
        float v = T[tx][ty + r * 8];
        if (fl) ((float*)out)[oi] = v;
        else    ((bf16*)out)[oi] = __float2bfloat16(v);
    }
}

// ---------------------------------------------------------------------------
extern "C" void kernel_launch(void* const* d_in, const int* in_sizes, int n_in,
                              void* d_out, int out_size, void* d_ws, size_t ws_size,
                              hipStream_t stream)
{
    const void* z1ss = d_in[0];
    const void* pos  = d_in[1];
    const void* u1ss = d_in[2];
    const void* Wqkv = d_in[3];
    const void* Wr   = d_in[4];
    const void* rwb  = d_in[5];
    const void* rrb  = d_in[6];
    const void* Wo   = d_in[7];
    const void* bo   = d_in[8];

    const size_t whE  = (size_t)BSZ * QKV3 * QLEN;     // 12,582,912 elems
    const size_t rhkE = (size_t)D_MODEL * QLEN;        //  2,097,152
    const size_t avE  = (size_t)BSZ * QLEN * D_MODEL;  //  4,194,304
    const size_t ztE  = avE;
    const size_t wqE  = (size_t)QKV3 * D_MODEL;        //  3,145,728
    const size_t wrE  = (size_t)D_MODEL * D_MODEL;     //  1,048,576
    const size_t woE  = wrE;

    char* ws = (char*)d_ws;
    bf16* wh   = (bf16*)ws;            // [B][3072][Q] o-major (q|k|v)
    bf16* rhk  = wh + whE;             // [1024][Q] o-major
    bf16* avec = rhk + rhkE;           // [B][Q][1024]
    bf16* post = avec;                 // overlay: dead before attn writes avec
    size_t baseB = (whE + rhkE + avE) * sizeof(bf16);
    bf16* zt  = (bf16*)(ws + baseB);
    bf16* wqb = zt + ztE;              // wqb|wrb|wob contiguous (convw_all)
    bf16* wrb = wqb + wqE;
    bf16* wob = wrb + wrE;
    float* yt = (float*)ws;            // overlays wh (dead after attn)

    const size_t t2B = baseB + ztE * sizeof(bf16) + 16;
    const size_t t1B = baseB + (ztE + wqE + wrE + woE) * sizeof(bf16) + 16;
    const int tier = (ws_size >= t1B) ? 1 : (ws_size >= t2B) ? 2 : 3;

    int* flag = (tier == 1) ? (int*)(wob + woE)
              : (tier == 2) ? (int*)(wqb)
                            : (int*)(ws + baseB);

    detect_kernel<<<1, 64, 0, stream>>>((const unsigned short*)Wqkv, flag);

    if (tier == 1) {
        // 0a. weights -> bf16 (one dispatch; outputs contiguous)
        convw_all<<<dim3((unsigned)((wqE + wrE + woE) / 2048)), 256, 0, stream>>>(
            Wqkv, Wr, Wo, wqb, flag);

        // 0b. transposes (one dispatch: z in [0,BSZ] with z==BSZ -> pos)
        tcvt_all<<<dim3(QLEN / 32, D_MODEL / 32, BSZ + 1), 256, 0, stream>>>(
            z1ss, pos, zt, post, flag);

        // 1+2. fused QKV + rhk GEMM (T4 counted-vmcnt, depth-2 prefetch)
        gemm_qkvr<<<dim3(QLEN / 128, QKV3 / 128 + D_MODEL / 128, BSZ), 256, 0, stream>>>(
            wqb, wrb, zt, post, wh, rhk, u1ss, flag);

        // 3. MFMA banded flash attention v8 -> avec[b][q][1024]
        attn_mfma<<<dim3(QLEN / 64, N_HEAD, BSZ), 256, 0, stream>>>(
            wh, rhk, rwb, rrb, avec, flag);

        // 4. y_t[b][q][o] = avec . Wo^T + bo + zt
        gemm_glds<<<dim3(1024 / 128, 2048 / 128, BSZ), 256, 0, stream>>>(
            avec, (size_t)QLEN * D_MODEL,
            wob, 0,
            yt, 0, (size_t)QLEN * D_MODEL,
            zt, 0, (size_t)QLEN * D_MODEL,
            bo, 2,
            QLEN, D_MODEL, D_MODEL, flag);
    } else if (tier == 2) {
        // proven round-2 path
        tcvt_all<<<dim3(QLEN / 32, D_MODEL / 32, BSZ + 1), 256, 0, stream>>>(
            z1ss, pos, zt, post, flag);

        gemm_bf16<<<dim3(2048 / 128, 3072 / 128, BSZ), 256, 0, stream>>>(
            Wqkv, 2, 0,
            zt, 0, (size_t)QLEN * D_MODEL,
            wh, 1, (size_t)QKV3 * QLEN,
            u1ss, 2, (size_t)QKV3 * QLEN,
            nullptr, 0,
            QKV3, QLEN, D_MODEL, flag);

        gemm_bf16<<<dim3(2048 / 128, 1024 / 128, 1), 256, 0, stream>>>(
            Wr, 2, 0,
            post, 0, 0,
            rhk, 1, 0,
            nullptr, 0, 0,
            nullptr, 0,
            D_MODEL, QLEN, D_MODEL, flag);

        attn_mfma<<<dim3(QLEN / 64, N_HEAD, BSZ), 256, 0, stream>>>(
            wh, rhk, rwb, rrb, avec, flag);

        gemm_bf16<<<dim3(1024 / 128, 2048 / 128, BSZ), 256, 0, stream>>>(
            avec, 0, (size_t)QLEN * D_MODEL,
            Wo, 2, 0,
            yt, 0, (size_t)QLEN * D_MODEL,
            zt, 0, (size_t)QLEN * D_MODEL,
            bo, 2,
            QLEN, D_MODEL, D_MODEL, flag);
    } else {
        // fallback: proven gemm_tn path (in-GEMM transpose) + attn
        gemm_tn<<<dim3(2048 / 128, 3072 / 128, BSZ), 256, 0, stream>>>(
            Wqkv, 2, 0,
            z1ss, 2, 1, QLEN, (size_t)D_MODEL * QLEN,
            wh, 1, (size_t)QKV3 * QLEN,
            u1ss, 2, 0, (size_t)QKV3 * QLEN,
            nullptr, 0,
            QKV3, QLEN, D_MODEL, flag);
        gemm_tn<<<dim3(2048 / 128, 1024 / 128, 1), 256, 0, stream>>>(
            Wr, 2, 0,
            pos, 2, 1, QLEN, 0,
            rhk, 1, 0,
            nullptr, 0, 0, 0,
            nullptr, 0,
            D_MODEL, QLEN, D_MODEL, flag);
        attn_mfma<<<dim3(QLEN / 64, N_HEAD, BSZ), 256, 0, stream>>>(
            wh, rhk, rwb, rrb, avec, flag);
        gemm_tn<<<dim3(1024 / 128, 2048 / 128, BSZ), 256, 0, stream>>>(
            avec, 0, (size_t)QLEN * D_MODEL,
            Wo, 2, 0, D_MODEL, 0,
            yt, 0, (size_t)QLEN * D_MODEL,
            z1ss, 2, 1, (size_t)D_MODEL * QLEN,
            bo, 2,
            QLEN, D_MODEL, D_MODEL, flag);
    }

    // 5. LN in place on y_t rows
    ln_kernel<<<dim3(QLEN, BSZ), 256, 0, stream>>>(yt);

    // 6. transpose to out[b][o][q]
    transpose_out<<<dim3(QLEN / 32, D_MODEL / 32, BSZ), 256, 0, stream>>>(yt, d_out, flag);
}